// Round 8
// baseline (1430.596 us; speedup 1.0000x reference)
//
#include <hip/hip_runtime.h>
#include <stdint.h>

static constexpr int NU    = 100000;
static constexpr int NI    = 200000;
static constexpr int D     = 64;
static constexpr int E_UI  = 3200000;
static constexpr int E_SOC = 1600000;
static constexpr int CH    = 8192;   // edges per binning block
static constexpr int BROWS = 512;    // rows per bucket
#define EPS_LN 1e-5f

__device__ __forceinline__ float b2f(unsigned short h) {
    union { unsigned u; float f; } c; c.u = (unsigned)h << 16; return c.f;
}
__device__ __forceinline__ unsigned short f2b(float f) {
    unsigned u = __float_as_uint(f);
    u = (u + 0x7FFFu + ((u >> 16) & 1u)) >> 16;   // RNE
    return (unsigned short)u;
}

// ---------- phase 1: per-block bucket histogram ----------
__global__ void __launch_bounds__(256) bin_count(
    const int* __restrict__ rows, int E, int nblk, int nb, int* __restrict__ cnt)
{
    __shared__ int hist[512];
    int b = blockIdx.x, t = threadIdx.x;
    for (int i = t; i < nb; i += 256) hist[i] = 0;
    __syncthreads();
    int e0 = b * CH, e1 = min(E, e0 + CH);
    for (int e = e0 + t; e < e1; e += 256)
        atomicAdd(&hist[rows[e] >> 9], 1);
    __syncthreads();
    for (int i = t; i < nb; i += 256) cnt[i * nblk + b] = hist[i];  // bucket-major
}

// ---------- generic 3-level exclusive scan ----------
__global__ void scan_partial(const int* __restrict__ cnt, int* __restrict__ bsum, int n)
{
    __shared__ int lds[256];
    int i = blockIdx.x * 256 + threadIdx.x;
    lds[threadIdx.x] = (i < n) ? cnt[i] : 0;
    __syncthreads();
    for (int off = 128; off > 0; off >>= 1) {
        if (threadIdx.x < off) lds[threadIdx.x] += lds[threadIdx.x + off];
        __syncthreads();
    }
    if (threadIdx.x == 0) bsum[blockIdx.x] = lds[0];
}

__global__ void scan_bsums(int* __restrict__ bsum, int nb)
{
    __shared__ int lds[1024];
    int t = threadIdx.x;
    int v = (t < nb) ? bsum[t] : 0;
    lds[t] = v;
    __syncthreads();
    for (int off = 1; off < 1024; off <<= 1) {
        int add = (t >= off) ? lds[t - off] : 0;
        __syncthreads();
        lds[t] += add;
        __syncthreads();
    }
    if (t < nb) bsum[t] = lds[t] - v;   // exclusive scan of block sums
}

__global__ void scan_out(const int* __restrict__ cnt, const int* __restrict__ bsum,
                         int* __restrict__ ofs, int n)
{
    __shared__ int lds[256];
    int i = blockIdx.x * 256 + threadIdx.x;
    int v = (i < n) ? cnt[i] : 0;
    lds[threadIdx.x] = v;
    __syncthreads();
    for (int off = 1; off < 256; off <<= 1) {
        int add = (threadIdx.x >= off) ? lds[threadIdx.x - off] : 0;
        __syncthreads();
        lds[threadIdx.x] += add;
        __syncthreads();
    }
    if (i < n) ofs[i] = bsum[blockIdx.x] + lds[threadIdx.x] - v;
}

// ---------- phase 2: bucket-binned scatter (LDS cursors, no global atomics) ----------
__global__ void __launch_bounds__(256) bin_scatter(
    const int* __restrict__ rows, const int* __restrict__ idxs, const float* __restrict__ vals,
    int E, int nblk, const int* __restrict__ ofs, int nb, int2* __restrict__ binned)
{
    __shared__ int cur[512];
    int b = blockIdx.x, t = threadIdx.x;
    for (int i = t; i < nb; i += 256) cur[i] = ofs[i * nblk + b];
    __syncthreads();
    int e0 = b * CH, e1 = min(E, e0 + CH);
    for (int e = e0 + t; e < e1; e += 256) {
        int row = rows[e];
        int bucket = row >> 9;
        int slot = atomicAdd(&cur[bucket], 1);
        unsigned pack = ((unsigned)(row & 511) << 23) | (unsigned)idxs[e];
        binned[slot] = make_int2((int)pack, __float_as_int(vals[e]));
    }
}

// ---------- phase 3: per-bucket fine scatter into row-sorted CSR ----------
__global__ void __launch_bounds__(512) fine_scatter(
    const int2* __restrict__ binned, const int* __restrict__ ofs, int nblk, int nb,
    int E, int nrows, int* __restrict__ rowptr, int2* __restrict__ rec)
{
    __shared__ int hist[512];
    __shared__ int cur[512];
    int b = blockIdx.x, t = threadIdx.x;
    int beg = ofs[b * nblk];
    int end = (b + 1 < nb) ? ofs[(b + 1) * nblk] : E;

    hist[t] = 0;
    __syncthreads();
    for (int j = beg + t; j < end; j += 512)
        atomicAdd(&hist[((unsigned)binned[j].x) >> 23], 1);
    __syncthreads();
    int v = hist[t];
    // inclusive Hillis-Steele scan over 512
    for (int off = 1; off < 512; off <<= 1) {
        int add = (t >= off) ? hist[t - off] : 0;
        __syncthreads();
        hist[t] += add;
        __syncthreads();
    }
    int excl = hist[t] - v;
    cur[t] = excl;
    int grow = b * BROWS + t;
    if (grow <= nrows) rowptr[grow] = beg + excl;   // covers rowptr[nrows]=E in last bucket
    __syncthreads();
    for (int j = beg + t; j < end; j += 512) {
        int2 eb = binned[j];
        unsigned p = (unsigned)eb.x;
        int rl  = (int)(p >> 23);
        int idx = (int)(p & 0x7FFFFFu);
        int c = atomicAdd(&cur[rl], 1);
        rec[beg + c] = make_int2(idx, eb.y);
    }
}

__global__ void copy0_kernel(const float4* __restrict__ src, float4* __restrict__ a,
                             float4* __restrict__ b, int n4)
{
    int i = blockIdx.x * blockDim.x + threadIdx.x;
    if (i < n4) { float4 v = src[i]; a[i] = v; b[i] = v; }
}

// fp32 -> bf16 table conversion
__global__ void f2b_kernel(const float4* __restrict__ src, ushort4* __restrict__ dst, int n4)
{
    int i = blockIdx.x * blockDim.x + threadIdx.x;
    if (i < n4) {
        float4 v = src[i];
        ushort4 h;
        h.x = f2b(v.x); h.y = f2b(v.y); h.z = f2b(v.z); h.w = f2b(v.w);
        dst[i] = h;
    }
}

// fused SPMM + GEMV(@W + bias) + residual + LayerNorm; one 64-lane wave per row.
// Gather source is a bf16 table: 16 lanes x bf16x4 (8B) per edge, 4 edges per
// wave instruction, 4x unrolled (16 edges in flight). Optionally emits a bf16
// copy of the output for the next layer's gather.
__global__ void __launch_bounds__(256) fused_layer(
    const float* __restrict__ xin, const unsigned short* __restrict__ gsrc,
    float* __restrict__ yout, unsigned short* __restrict__ yout_b,
    const int* __restrict__ rowptr, const int2* __restrict__ recs,
    const float* __restrict__ W, const float* __restrict__ bias,
    const float* __restrict__ gamma, const float* __restrict__ beta,
    int nrows)
{
    __shared__ float Wl[64 * 64];
    {
        const float4* W4 = (const float4*)W;
        float4* Wl4 = (float4*)Wl;
        for (int i = threadIdx.x; i < 1024; i += 256) Wl4[i] = W4[i];
    }
    __syncthreads();
    int wid  = (blockIdx.x * 256 + threadIdx.x) >> 6;
    int lane = threadIdx.x & 63;
    if (wid >= nrows) return;

    int g   = lane >> 4;    // edge sub-group 0..3
    int l16 = lane & 15;    // bf16x4 index within row

    float4 a0 = make_float4(0.f, 0.f, 0.f, 0.f);
    float4 a1 = make_float4(0.f, 0.f, 0.f, 0.f);
    float4 a2 = make_float4(0.f, 0.f, 0.f, 0.f);
    float4 a3 = make_float4(0.f, 0.f, 0.f, 0.f);
    int beg = rowptr[wid], end = rowptr[wid + 1];
    int j = beg + g;
    for (; j + 12 < end; j += 16) {
        int2 r0 = recs[j];
        int2 r1 = recs[j + 4];
        int2 r2 = recs[j + 8];
        int2 r3 = recs[j + 12];
        ushort4 h0 = ((const ushort4*)(gsrc + (size_t)r0.x * 64))[l16];
        ushort4 h1 = ((const ushort4*)(gsrc + (size_t)r1.x * 64))[l16];
        ushort4 h2 = ((const ushort4*)(gsrc + (size_t)r2.x * 64))[l16];
        ushort4 h3 = ((const ushort4*)(gsrc + (size_t)r3.x * 64))[l16];
        float w0 = __int_as_float(r0.y), w1 = __int_as_float(r1.y);
        float w2 = __int_as_float(r2.y), w3 = __int_as_float(r3.y);
        a0.x += w0 * b2f(h0.x); a0.y += w0 * b2f(h0.y); a0.z += w0 * b2f(h0.z); a0.w += w0 * b2f(h0.w);
        a1.x += w1 * b2f(h1.x); a1.y += w1 * b2f(h1.y); a1.z += w1 * b2f(h1.z); a1.w += w1 * b2f(h1.w);
        a2.x += w2 * b2f(h2.x); a2.y += w2 * b2f(h2.y); a2.z += w2 * b2f(h2.z); a2.w += w2 * b2f(h2.w);
        a3.x += w3 * b2f(h3.x); a3.y += w3 * b2f(h3.y); a3.z += w3 * b2f(h3.z); a3.w += w3 * b2f(h3.w);
    }
    for (; j < end; j += 4) {
        int2 r0 = recs[j];
        ushort4 h0 = ((const ushort4*)(gsrc + (size_t)r0.x * 64))[l16];
        float w0 = __int_as_float(r0.y);
        a0.x += w0 * b2f(h0.x); a0.y += w0 * b2f(h0.y); a0.z += w0 * b2f(h0.z); a0.w += w0 * b2f(h0.w);
    }
    float4 acc = make_float4(a0.x + a1.x + a2.x + a3.x,
                             a0.y + a1.y + a2.y + a3.y,
                             a0.z + a1.z + a2.z + a3.z,
                             a0.w + a1.w + a2.w + a3.w);
    // reduce across the 4 edge sub-groups (XOR butterfly over lanes 16, 32)
    #pragma unroll
    for (int off = 16; off <= 32; off <<= 1) {
        acc.x += __shfl_xor(acc.x, off);
        acc.y += __shfl_xor(acc.y, off);
        acc.z += __shfl_xor(acc.z, off);
        acc.w += __shfl_xor(acc.w, off);
    }
    // lane l16==q holds agg dims 4q..4q+3 (replicated across groups)

    // GEMV: z[lane] = bias[lane] + sum_k agg[k] * W[k][lane]
    float z = bias[lane];
    #pragma unroll
    for (int q = 0; q < 16; ++q) {
        float c0 = __shfl(acc.x, q);
        float c1 = __shfl(acc.y, q);
        float c2 = __shfl(acc.z, q);
        float c3 = __shfl(acc.w, q);
        z += c0 * Wl[(4 * q + 0) * 64 + lane];
        z += c1 * Wl[(4 * q + 1) * 64 + lane];
        z += c2 * Wl[(4 * q + 2) * 64 + lane];
        z += c3 * Wl[(4 * q + 3) * 64 + lane];
    }
    // residual + LayerNorm across the 64 lanes
    float t = xin[wid * 64 + lane] + z;
    float s = t;
    #pragma unroll
    for (int off = 32; off > 0; off >>= 1) s += __shfl_xor(s, off);
    float mean = s * (1.0f / 64.0f);
    float dv = t - mean;
    float q2 = dv * dv;
    #pragma unroll
    for (int off = 32; off > 0; off >>= 1) q2 += __shfl_xor(q2, off);
    float var = q2 * (1.0f / 64.0f);
    float y = dv * rsqrtf(var + EPS_LN) * gamma[lane] + beta[lane];
    yout[wid * 64 + lane] = y;
    if (yout_b) yout_b[wid * 64 + lane] = f2b(y);
}

extern "C" void kernel_launch(void* const* d_in, const int* in_sizes, int n_in,
                              void* d_out, int out_size, void* d_ws, size_t ws_size,
                              hipStream_t stream)
{
    const float* user_emb = (const float*)d_in[0];
    const float* item_emb = (const float*)d_in[1];
    const int*   ui_src   = (const int*)d_in[2];
    const int*   ui_dst   = (const int*)d_in[3];
    const float* ui_val   = (const float*)d_in[4];
    const int*   soc_src  = (const int*)d_in[5];
    const int*   soc_dst  = (const int*)d_in[6];
    const float* soc_val  = (const float*)d_in[7];
    const float* W_ui     = (const float*)d_in[8];
    const float* b_ui     = (const float*)d_in[9];
    const float* W_soc    = (const float*)d_in[10];
    const float* b_soc    = (const float*)d_in[11];
    const float* ln_g     = (const float*)d_in[12];
    const float* ln_b     = (const float*)d_in[13];

    float* out     = (float*)d_out;
    float* out_ui  = out;                         // [3][NU][D]
    float* out_soc = out + (size_t)3 * NU * D;    // [3][NU][D]
    float* out_it  = out + (size_t)6 * NU * D;    // [NI][D]

    // bucket/block geometry
    const int NBU = (NU + BROWS - 1) / BROWS;     // 196 user buckets
    const int NBI = (NI + BROWS - 1) / BROWS;     // 391 item buckets
    const int BLK_UI  = (E_UI  + CH - 1) / CH;    // 391
    const int BLK_SOC = (E_SOC + CH - 1) / CH;    // 196

    // ---- workspace carve (256B-aligned) ----
    char* p = (char*)d_ws;
    auto take = [&](size_t bytes) { char* r = p; p += (bytes + 255) & ~(size_t)255; return r; };
    int2* rec_us = (int2*)take((size_t)E_UI * 8);
    int2* rec_ud = (int2*)take((size_t)E_UI * 8);
    int2* rec_ss = (int2*)take((size_t)E_SOC * 8);
    int2* binned = (int2*)take((size_t)E_UI * 8);      // reused by all three tasks
    int*  rp_us  = (int*)take((size_t)(NU + 1) * 4);
    int*  rp_ud  = (int*)take((size_t)(NI + 1) * 4);
    int*  rp_ss  = (int*)take((size_t)(NU + 1) * 4);
    int*  cnt    = (int*)take((size_t)NBI * BLK_UI * 4);   // max 152881
    int*  ofs    = (int*)take((size_t)NBI * BLK_UI * 4);
    int*  bsum   = (int*)take(1024 * 4);
    // bf16 gather tables
    unsigned short* u0b  = (unsigned short*)take((size_t)NU * D * 2);  // user_emb bf16
    unsigned short* it0b = (unsigned short*)take((size_t)NI * D * 2);  // item_emb bf16; reused as it1b
    unsigned short* u1b  = (unsigned short*)take((size_t)NU * D * 2);
    unsigned short* s1b  = (unsigned short*)take((size_t)NU * D * 2);
    unsigned short* it1b = it0b;  // safe: overwritten by item-layer0 AFTER user-layer0 consumed it0b

    auto build_csr = [&](const int* rows, const int* idxs, const float* vals,
                         int E, int nblk, int nb, int nrows, int* rowptr, int2* rec) {
        bin_count<<<nblk, 256, 0, stream>>>(rows, E, nblk, nb, cnt);
        int n = nb * nblk;
        int sb = (n + 255) / 256;
        scan_partial<<<sb, 256, 0, stream>>>(cnt, bsum, n);
        scan_bsums<<<1, 1024, 0, stream>>>(bsum, sb);
        scan_out<<<sb, 256, 0, stream>>>(cnt, bsum, ofs, n);
        bin_scatter<<<nblk, 256, 0, stream>>>(rows, idxs, vals, E, nblk, ofs, nb, binned);
        fine_scatter<<<nb, 512, 0, stream>>>(binned, ofs, nblk, nb, E, nrows, rowptr, rec);
    };

    build_csr(ui_src,  ui_dst,  ui_val,  E_UI,  BLK_UI,  NBU, NU, rp_us, rec_us);
    build_csr(ui_dst,  ui_src,  ui_val,  E_UI,  BLK_UI,  NBI, NI, rp_ud, rec_ud);
    build_csr(soc_src, soc_dst, soc_val, E_SOC, BLK_SOC, NBU, NU, rp_ss, rec_ss);

    // ---- bf16 tables for layer-0 gathers ----
    f2b_kernel<<<(NU * 16 + 255) / 256, 256, 0, stream>>>((const float4*)user_emb,
                                                          (ushort4*)u0b, NU * 16);
    f2b_kernel<<<(NI * 16 + 255) / 256, 256, 0, stream>>>((const float4*)item_emb,
                                                          (ushort4*)it0b, NI * 16);

    // ---- layer 0 outputs: ui_list[0] = soc_list[0] = user_emb ----
    int n4 = NU * D / 4;
    copy0_kernel<<<(n4 + 255) / 256, 256, 0, stream>>>((const float4*)user_emb,
                                                       (float4*)out_ui, (float4*)out_soc, n4);

    const float* u0 = user_emb;
    float* u1 = out_ui + (size_t)NU * D;
    float* u2 = out_ui + (size_t)2 * NU * D;
    const float* s0 = user_emb;
    float* s1 = out_soc + (size_t)NU * D;
    float* s2 = out_soc + (size_t)2 * NU * D;

    int ublocks = (NU + 3) / 4;   // 4 waves per 256-thread block
    int iblocks = (NI + 3) / 4;

    // ---- layer 0 ----
    // users: u1 = LN(u0 + spmm(ui_by_src, it0) @ W_ui[0] + b; ln[0])   [reads it0b]
    fused_layer<<<ublocks, 256, 0, stream>>>(u0, it0b, u1, u1b, rp_us, rec_us,
                                             W_ui + 0 * 4096, b_ui + 0 * 64,
                                             ln_g + 0 * 64, ln_b + 0 * 64, NU);
    // items: it1 = LN(it0 + spmm(ui_by_dst, u0) @ W_ui[0] + b; ln[1])  [reads u0b, writes it1b=it0b]
    fused_layer<<<iblocks, 256, 0, stream>>>(item_emb, u0b, out_it, it1b, rp_ud, rec_ud,
                                             W_ui + 0 * 4096, b_ui + 0 * 64,
                                             ln_g + 1 * 64, ln_b + 1 * 64, NI);
    // social: s1 = LN(s0 + spmm(soc_by_src, s0) @ W_soc[0] + b; ln[0]) [reads u0b]
    fused_layer<<<ublocks, 256, 0, stream>>>(s0, u0b, s1, s1b, rp_ss, rec_ss,
                                             W_soc + 0 * 4096, b_soc + 0 * 64,
                                             ln_g + 0 * 64, ln_b + 0 * 64, NU);

    // ---- layer 1 (no bf16 outputs needed) ----
    fused_layer<<<ublocks, 256, 0, stream>>>(u1, it1b, u2, nullptr, rp_us, rec_us,
                                             W_ui + 1 * 4096, b_ui + 1 * 64,
                                             ln_g + 2 * 64, ln_b + 2 * 64, NU);
    fused_layer<<<iblocks, 256, 0, stream>>>(out_it, u1b, out_it, nullptr, rp_ud, rec_ud,
                                             W_ui + 1 * 4096, b_ui + 1 * 64,
                                             ln_g + 3 * 64, ln_b + 3 * 64, NI);
    fused_layer<<<ublocks, 256, 0, stream>>>(s1, s1b, s2, nullptr, rp_ss, rec_ss,
                                             W_soc + 1 * 4096, b_soc + 1 * 64,
                                             ln_g + 2 * 64, ln_b + 2 * 64, NU);
}

// Round 9
// 1411.341 us; speedup vs baseline: 1.0136x; 1.0136x over previous
//
#include <hip/hip_runtime.h>
#include <stdint.h>

static constexpr int NU    = 100000;
static constexpr int NI    = 200000;
static constexpr int D     = 64;
static constexpr int E_UI  = 3200000;
static constexpr int E_SOC = 1600000;
static constexpr int CH    = 8192;   // edges per binning block
static constexpr int BROWS = 512;    // rows per bucket
#define EPS_LN 1e-5f

__device__ __forceinline__ float b2f(unsigned short h) {
    union { unsigned u; float f; } c; c.u = (unsigned)h << 16; return c.f;
}
__device__ __forceinline__ unsigned short f2b(float f) {
    unsigned u = __float_as_uint(f);
    u = (u + 0x7FFFu + ((u >> 16) & 1u)) >> 16;   // RNE
    return (unsigned short)u;
}
__device__ __forceinline__ float b2f_lo(unsigned u) { return __uint_as_float(u << 16); }
__device__ __forceinline__ float b2f_hi(unsigned u) { return __uint_as_float(u & 0xFFFF0000u); }

// ---------- phase 1: per-block bucket histogram ----------
__global__ void __launch_bounds__(256) bin_count(
    const int* __restrict__ rows, int E, int nblk, int nb, int* __restrict__ cnt)
{
    __shared__ int hist[512];
    int b = blockIdx.x, t = threadIdx.x;
    for (int i = t; i < nb; i += 256) hist[i] = 0;
    __syncthreads();
    int e0 = b * CH, e1 = min(E, e0 + CH);
    for (int e = e0 + t; e < e1; e += 256)
        atomicAdd(&hist[rows[e] >> 9], 1);
    __syncthreads();
    for (int i = t; i < nb; i += 256) cnt[i * nblk + b] = hist[i];  // bucket-major
}

// ---------- generic 3-level exclusive scan ----------
__global__ void scan_partial(const int* __restrict__ cnt, int* __restrict__ bsum, int n)
{
    __shared__ int lds[256];
    int i = blockIdx.x * 256 + threadIdx.x;
    lds[threadIdx.x] = (i < n) ? cnt[i] : 0;
    __syncthreads();
    for (int off = 128; off > 0; off >>= 1) {
        if (threadIdx.x < off) lds[threadIdx.x] += lds[threadIdx.x + off];
        __syncthreads();
    }
    if (threadIdx.x == 0) bsum[blockIdx.x] = lds[0];
}

__global__ void scan_bsums(int* __restrict__ bsum, int nb)
{
    __shared__ int lds[1024];
    int t = threadIdx.x;
    int v = (t < nb) ? bsum[t] : 0;
    lds[t] = v;
    __syncthreads();
    for (int off = 1; off < 1024; off <<= 1) {
        int add = (t >= off) ? lds[t - off] : 0;
        __syncthreads();
        lds[t] += add;
        __syncthreads();
    }
    if (t < nb) bsum[t] = lds[t] - v;   // exclusive scan of block sums
}

__global__ void scan_out(const int* __restrict__ cnt, const int* __restrict__ bsum,
                         int* __restrict__ ofs, int n)
{
    __shared__ int lds[256];
    int i = blockIdx.x * 256 + threadIdx.x;
    int v = (i < n) ? cnt[i] : 0;
    lds[threadIdx.x] = v;
    __syncthreads();
    for (int off = 1; off < 256; off <<= 1) {
        int add = (threadIdx.x >= off) ? lds[threadIdx.x - off] : 0;
        __syncthreads();
        lds[threadIdx.x] += add;
        __syncthreads();
    }
    if (i < n) ofs[i] = bsum[blockIdx.x] + lds[threadIdx.x] - v;
}

// ---------- phase 2: bucket-binned scatter (LDS cursors, no global atomics) ----------
__global__ void __launch_bounds__(256) bin_scatter(
    const int* __restrict__ rows, const int* __restrict__ idxs, const float* __restrict__ vals,
    int E, int nblk, const int* __restrict__ ofs, int nb, int2* __restrict__ binned)
{
    __shared__ int cur[512];
    int b = blockIdx.x, t = threadIdx.x;
    for (int i = t; i < nb; i += 256) cur[i] = ofs[i * nblk + b];
    __syncthreads();
    int e0 = b * CH, e1 = min(E, e0 + CH);
    for (int e = e0 + t; e < e1; e += 256) {
        int row = rows[e];
        int bucket = row >> 9;
        int slot = atomicAdd(&cur[bucket], 1);
        unsigned pack = ((unsigned)(row & 511) << 23) | (unsigned)idxs[e];
        binned[slot] = make_int2((int)pack, __float_as_int(vals[e]));
    }
}

// ---------- phase 3: per-bucket fine scatter into row-sorted CSR ----------
__global__ void __launch_bounds__(512) fine_scatter(
    const int2* __restrict__ binned, const int* __restrict__ ofs, int nblk, int nb,
    int E, int nrows, int* __restrict__ rowptr, int2* __restrict__ rec)
{
    __shared__ int hist[512];
    __shared__ int cur[512];
    int b = blockIdx.x, t = threadIdx.x;
    int beg = ofs[b * nblk];
    int end = (b + 1 < nb) ? ofs[(b + 1) * nblk] : E;

    hist[t] = 0;
    __syncthreads();
    for (int j = beg + t; j < end; j += 512)
        atomicAdd(&hist[((unsigned)binned[j].x) >> 23], 1);
    __syncthreads();
    int v = hist[t];
    for (int off = 1; off < 512; off <<= 1) {
        int add = (t >= off) ? hist[t - off] : 0;
        __syncthreads();
        hist[t] += add;
        __syncthreads();
    }
    int excl = hist[t] - v;
    cur[t] = excl;
    int grow = b * BROWS + t;
    if (grow <= nrows) rowptr[grow] = beg + excl;   // covers rowptr[nrows]=E in last bucket
    __syncthreads();
    for (int j = beg + t; j < end; j += 512) {
        int2 eb = binned[j];
        unsigned p = (unsigned)eb.x;
        int rl  = (int)(p >> 23);
        int idx = (int)(p & 0x7FFFFFu);
        int c = atomicAdd(&cur[rl], 1);
        rec[beg + c] = make_int2(idx, eb.y);
    }
}

__global__ void copy0_kernel(const float4* __restrict__ src, float4* __restrict__ a,
                             float4* __restrict__ b, int n4)
{
    int i = blockIdx.x * blockDim.x + threadIdx.x;
    if (i < n4) { float4 v = src[i]; a[i] = v; b[i] = v; }
}

// fp32 -> bf16 table conversion
__global__ void f2b_kernel(const float4* __restrict__ src, ushort4* __restrict__ dst, int n4)
{
    int i = blockIdx.x * blockDim.x + threadIdx.x;
    if (i < n4) {
        float4 v = src[i];
        ushort4 h;
        h.x = f2b(v.x); h.y = f2b(v.y); h.z = f2b(v.z); h.w = f2b(v.w);
        dst[i] = h;
    }
}

struct TaskDesc {
    const float* xin;
    const unsigned short* gsrc;
    float* yout;
    unsigned short* youtb;
    const int* rowptr;
    const int2* recs;
    const float* W;
    const float* bias;
    const float* gamma;
    const float* beta;
    int nrows;
    int blk0;   // first block index of this task
};

// 3 independent fused tasks in one dispatch. One 64-lane wave per row.
// Gather: 8 lanes x ushort8 (16B) per edge row -> 8 edges per wave instr,
// 2x unrolled (16 edges in flight).
__global__ void __launch_bounds__(256) fused_layer3(TaskDesc t0, TaskDesc t1, TaskDesc t2)
{
    __shared__ float Wl[64 * 64];
    TaskDesc t = (blockIdx.x >= (unsigned)t2.blk0) ? t2
               : (blockIdx.x >= (unsigned)t1.blk0) ? t1 : t0;
    {
        const float4* W4 = (const float4*)t.W;
        float4* Wl4 = (float4*)Wl;
        for (int i = threadIdx.x; i < 1024; i += 256) Wl4[i] = W4[i];
    }
    __syncthreads();
    int lblk = blockIdx.x - t.blk0;
    int wid  = lblk * 4 + (threadIdx.x >> 6);
    int lane = threadIdx.x & 63;
    if (wid >= t.nrows) return;

    int g  = lane >> 3;   // edge sub-group 0..7
    int l8 = lane & 7;    // ushort8 slot within row (dims 8*l8 .. 8*l8+7)

    float a0[8], a1[8];
    #pragma unroll
    for (int m = 0; m < 8; ++m) { a0[m] = 0.f; a1[m] = 0.f; }

    int beg = t.rowptr[wid], end = t.rowptr[wid + 1];
    int j = beg + g;
    for (; j + 8 < end; j += 16) {
        int2 r0 = t.recs[j];
        int2 r1 = t.recs[j + 8];
        uint4 h0 = ((const uint4*)(t.gsrc + (size_t)r0.x * 64))[l8];
        uint4 h1 = ((const uint4*)(t.gsrc + (size_t)r1.x * 64))[l8];
        float w0 = __int_as_float(r0.y);
        float w1 = __int_as_float(r1.y);
        a0[0] += w0 * b2f_lo(h0.x); a0[1] += w0 * b2f_hi(h0.x);
        a0[2] += w0 * b2f_lo(h0.y); a0[3] += w0 * b2f_hi(h0.y);
        a0[4] += w0 * b2f_lo(h0.z); a0[5] += w0 * b2f_hi(h0.z);
        a0[6] += w0 * b2f_lo(h0.w); a0[7] += w0 * b2f_hi(h0.w);
        a1[0] += w1 * b2f_lo(h1.x); a1[1] += w1 * b2f_hi(h1.x);
        a1[2] += w1 * b2f_lo(h1.y); a1[3] += w1 * b2f_hi(h1.y);
        a1[4] += w1 * b2f_lo(h1.z); a1[5] += w1 * b2f_hi(h1.z);
        a1[6] += w1 * b2f_lo(h1.w); a1[7] += w1 * b2f_hi(h1.w);
    }
    for (; j < end; j += 8) {
        int2 r0 = t.recs[j];
        uint4 h0 = ((const uint4*)(t.gsrc + (size_t)r0.x * 64))[l8];
        float w0 = __int_as_float(r0.y);
        a0[0] += w0 * b2f_lo(h0.x); a0[1] += w0 * b2f_hi(h0.x);
        a0[2] += w0 * b2f_lo(h0.y); a0[3] += w0 * b2f_hi(h0.y);
        a0[4] += w0 * b2f_lo(h0.z); a0[5] += w0 * b2f_hi(h0.z);
        a0[6] += w0 * b2f_lo(h0.w); a0[7] += w0 * b2f_hi(h0.w);
    }
    float acc[8];
    #pragma unroll
    for (int m = 0; m < 8; ++m) acc[m] = a0[m] + a1[m];
    // reduce across the 8 edge sub-groups (XOR butterfly over lanes 8,16,32)
    #pragma unroll
    for (int off = 8; off <= 32; off <<= 1)
        #pragma unroll
        for (int m = 0; m < 8; ++m)
            acc[m] += __shfl_xor(acc[m], off);
    // every lane now holds agg dims 8*(lane&7)+m

    // GEMV: z[lane] = bias[lane] + sum_k agg[k] * W[k][lane]
    float z = t.bias[lane];
    #pragma unroll
    for (int q = 0; q < 8; ++q)
        #pragma unroll
        for (int m = 0; m < 8; ++m)
            z += __shfl(acc[m], q) * Wl[(8 * q + m) * 64 + lane];

    // residual + LayerNorm across the 64 lanes
    float tt = t.xin[(size_t)wid * 64 + lane] + z;
    float s = tt;
    #pragma unroll
    for (int off = 32; off > 0; off >>= 1) s += __shfl_xor(s, off);
    float mean = s * (1.0f / 64.0f);
    float dv = tt - mean;
    float q2 = dv * dv;
    #pragma unroll
    for (int off = 32; off > 0; off >>= 1) q2 += __shfl_xor(q2, off);
    float var = q2 * (1.0f / 64.0f);
    float y = dv * rsqrtf(var + EPS_LN) * t.gamma[lane] + t.beta[lane];
    t.yout[(size_t)wid * 64 + lane] = y;
    if (t.youtb) t.youtb[(size_t)wid * 64 + lane] = f2b(y);
}

extern "C" void kernel_launch(void* const* d_in, const int* in_sizes, int n_in,
                              void* d_out, int out_size, void* d_ws, size_t ws_size,
                              hipStream_t stream)
{
    const float* user_emb = (const float*)d_in[0];
    const float* item_emb = (const float*)d_in[1];
    const int*   ui_src   = (const int*)d_in[2];
    const int*   ui_dst   = (const int*)d_in[3];
    const float* ui_val   = (const float*)d_in[4];
    const int*   soc_src  = (const int*)d_in[5];
    const int*   soc_dst  = (const int*)d_in[6];
    const float* soc_val  = (const float*)d_in[7];
    const float* W_ui     = (const float*)d_in[8];
    const float* b_ui     = (const float*)d_in[9];
    const float* W_soc    = (const float*)d_in[10];
    const float* b_soc    = (const float*)d_in[11];
    const float* ln_g     = (const float*)d_in[12];
    const float* ln_b     = (const float*)d_in[13];

    float* out     = (float*)d_out;
    float* out_ui  = out;                         // [3][NU][D]
    float* out_soc = out + (size_t)3 * NU * D;    // [3][NU][D]
    float* out_it  = out + (size_t)6 * NU * D;    // [NI][D]

    // bucket/block geometry
    const int NBU = (NU + BROWS - 1) / BROWS;     // 196 user buckets
    const int NBI = (NI + BROWS - 1) / BROWS;     // 391 item buckets
    const int BLK_UI  = (E_UI  + CH - 1) / CH;    // 391
    const int BLK_SOC = (E_SOC + CH - 1) / CH;    // 196

    // ---- workspace carve (256B-aligned) ----
    char* p = (char*)d_ws;
    auto take = [&](size_t bytes) { char* r = p; p += (bytes + 255) & ~(size_t)255; return r; };
    int2* rec_us = (int2*)take((size_t)E_UI * 8);
    int2* rec_ud = (int2*)take((size_t)E_UI * 8);
    int2* rec_ss = (int2*)take((size_t)E_SOC * 8);
    int2* binned = (int2*)take((size_t)E_UI * 8);      // CSR staging; reused as it1b after
    int*  rp_us  = (int*)take((size_t)(NU + 1) * 4);
    int*  rp_ud  = (int*)take((size_t)(NI + 1) * 4);
    int*  rp_ss  = (int*)take((size_t)(NU + 1) * 4);
    int*  cnt    = (int*)take((size_t)NBI * BLK_UI * 4);   // max 152881
    int*  ofs    = (int*)take((size_t)NBI * BLK_UI * 4);
    int*  bsum   = (int*)take(1024 * 4);
    // bf16 gather tables
    unsigned short* u0b  = (unsigned short*)take((size_t)NU * D * 2);  // user_emb bf16
    unsigned short* it0b = (unsigned short*)take((size_t)NI * D * 2);  // item_emb bf16
    unsigned short* u1b  = (unsigned short*)take((size_t)NU * D * 2);
    unsigned short* s1b  = (unsigned short*)take((size_t)NU * D * 2);
    unsigned short* it1b = (unsigned short*)binned;  // binned (25.6MB) dead after CSR build; NI*D*2 = 25.6MB

    auto build_csr = [&](const int* rows, const int* idxs, const float* vals,
                         int E, int nblk, int nb, int nrows, int* rowptr, int2* rec) {
        bin_count<<<nblk, 256, 0, stream>>>(rows, E, nblk, nb, cnt);
        int n = nb * nblk;
        int sb = (n + 255) / 256;
        scan_partial<<<sb, 256, 0, stream>>>(cnt, bsum, n);
        scan_bsums<<<1, 1024, 0, stream>>>(bsum, sb);
        scan_out<<<sb, 256, 0, stream>>>(cnt, bsum, ofs, n);
        bin_scatter<<<nblk, 256, 0, stream>>>(rows, idxs, vals, E, nblk, ofs, nb, binned);
        fine_scatter<<<nb, 512, 0, stream>>>(binned, ofs, nblk, nb, E, nrows, rowptr, rec);
    };

    build_csr(ui_src,  ui_dst,  ui_val,  E_UI,  BLK_UI,  NBU, NU, rp_us, rec_us);
    build_csr(ui_dst,  ui_src,  ui_val,  E_UI,  BLK_UI,  NBI, NI, rp_ud, rec_ud);
    build_csr(soc_src, soc_dst, soc_val, E_SOC, BLK_SOC, NBU, NU, rp_ss, rec_ss);

    // ---- bf16 tables for layer-0 gathers ----
    f2b_kernel<<<(NU * 16 + 255) / 256, 256, 0, stream>>>((const float4*)user_emb,
                                                          (ushort4*)u0b, NU * 16);
    f2b_kernel<<<(NI * 16 + 255) / 256, 256, 0, stream>>>((const float4*)item_emb,
                                                          (ushort4*)it0b, NI * 16);

    // ---- layer 0 outputs: ui_list[0] = soc_list[0] = user_emb ----
    int n4 = NU * D / 4;
    copy0_kernel<<<(n4 + 255) / 256, 256, 0, stream>>>((const float4*)user_emb,
                                                       (float4*)out_ui, (float4*)out_soc, n4);

    const float* u0 = user_emb;
    float* u1 = out_ui + (size_t)NU * D;
    float* u2 = out_ui + (size_t)2 * NU * D;
    const float* s0 = user_emb;
    float* s1 = out_soc + (size_t)NU * D;
    float* s2 = out_soc + (size_t)2 * NU * D;

    int ublocks = (NU + 3) / 4;   // 25000
    int iblocks = (NI + 3) / 4;   // 50000

    // ---- layer 0: one merged dispatch (item first — longest task) ----
    {
        TaskDesc ti { item_emb, u0b, out_it, it1b, rp_ud, rec_ud,
                      W_ui + 0 * 4096, b_ui + 0 * 64, ln_g + 1 * 64, ln_b + 1 * 64,
                      NI, 0 };
        TaskDesc tu { u0, it0b, u1, u1b, rp_us, rec_us,
                      W_ui + 0 * 4096, b_ui + 0 * 64, ln_g + 0 * 64, ln_b + 0 * 64,
                      NU, iblocks };
        TaskDesc ts { s0, u0b, s1, s1b, rp_ss, rec_ss,
                      W_soc + 0 * 4096, b_soc + 0 * 64, ln_g + 0 * 64, ln_b + 0 * 64,
                      NU, iblocks + ublocks };
        fused_layer3<<<iblocks + 2 * ublocks, 256, 0, stream>>>(ti, tu, ts);
    }

    // ---- layer 1: one merged dispatch ----
    {
        TaskDesc ti { out_it, u1b, out_it, nullptr, rp_ud, rec_ud,
                      W_ui + 1 * 4096, b_ui + 1 * 64, ln_g + 3 * 64, ln_b + 3 * 64,
                      NI, 0 };
        TaskDesc tu { u1, it1b, u2, nullptr, rp_us, rec_us,
                      W_ui + 1 * 4096, b_ui + 1 * 64, ln_g + 2 * 64, ln_b + 2 * 64,
                      NU, iblocks };
        TaskDesc ts { s1, s1b, s2, nullptr, rp_ss, rec_ss,
                      W_soc + 1 * 4096, b_soc + 1 * 64, ln_g + 2 * 64, ln_b + 2 * 64,
                      NU, iblocks + ublocks };
        fused_layer3<<<iblocks + 2 * ublocks, 256, 0, stream>>>(ti, tu, ts);
    }
}

// Round 10
// 1184.453 us; speedup vs baseline: 1.2078x; 1.1916x over previous
//
#include <hip/hip_runtime.h>
#include <stdint.h>

static constexpr int NU    = 100000;
static constexpr int NI    = 200000;
static constexpr int D     = 64;
static constexpr int E_UI  = 3200000;
static constexpr int E_SOC = 1600000;
static constexpr int CH    = 8192;   // edges per binning block
static constexpr int BROWS = 512;    // rows per bucket
#define EPS_LN 1e-5f

__device__ __forceinline__ unsigned short f2b(float f) {
    unsigned u = __float_as_uint(f);
    u = (u + 0x7FFFu + ((u >> 16) & 1u)) >> 16;   // RNE
    return (unsigned short)u;
}
__device__ __forceinline__ float b2f_lo(unsigned u) { return __uint_as_float(u << 16); }
__device__ __forceinline__ float b2f_hi(unsigned u) { return __uint_as_float(u & 0xFFFF0000u); }

// ---------- CSR build (unchanged) ----------
__global__ void __launch_bounds__(256) bin_count(
    const int* __restrict__ rows, int E, int nblk, int nb, int* __restrict__ cnt)
{
    __shared__ int hist[512];
    int b = blockIdx.x, t = threadIdx.x;
    for (int i = t; i < nb; i += 256) hist[i] = 0;
    __syncthreads();
    int e0 = b * CH, e1 = min(E, e0 + CH);
    for (int e = e0 + t; e < e1; e += 256)
        atomicAdd(&hist[rows[e] >> 9], 1);
    __syncthreads();
    for (int i = t; i < nb; i += 256) cnt[i * nblk + b] = hist[i];  // bucket-major
}

__global__ void scan_partial(const int* __restrict__ cnt, int* __restrict__ bsum, int n)
{
    __shared__ int lds[256];
    int i = blockIdx.x * 256 + threadIdx.x;
    lds[threadIdx.x] = (i < n) ? cnt[i] : 0;
    __syncthreads();
    for (int off = 128; off > 0; off >>= 1) {
        if (threadIdx.x < off) lds[threadIdx.x] += lds[threadIdx.x + off];
        __syncthreads();
    }
    if (threadIdx.x == 0) bsum[blockIdx.x] = lds[0];
}

__global__ void scan_bsums(int* __restrict__ bsum, int nb)
{
    __shared__ int lds[1024];
    int t = threadIdx.x;
    int v = (t < nb) ? bsum[t] : 0;
    lds[t] = v;
    __syncthreads();
    for (int off = 1; off < 1024; off <<= 1) {
        int add = (t >= off) ? lds[t - off] : 0;
        __syncthreads();
        lds[t] += add;
        __syncthreads();
    }
    if (t < nb) bsum[t] = lds[t] - v;
}

__global__ void scan_out(const int* __restrict__ cnt, const int* __restrict__ bsum,
                         int* __restrict__ ofs, int n)
{
    __shared__ int lds[256];
    int i = blockIdx.x * 256 + threadIdx.x;
    int v = (i < n) ? cnt[i] : 0;
    lds[threadIdx.x] = v;
    __syncthreads();
    for (int off = 1; off < 256; off <<= 1) {
        int add = (threadIdx.x >= off) ? lds[threadIdx.x - off] : 0;
        __syncthreads();
        lds[threadIdx.x] += add;
        __syncthreads();
    }
    if (i < n) ofs[i] = bsum[blockIdx.x] + lds[threadIdx.x] - v;
}

__global__ void __launch_bounds__(256) bin_scatter(
    const int* __restrict__ rows, const int* __restrict__ idxs, const float* __restrict__ vals,
    int E, int nblk, const int* __restrict__ ofs, int nb, int2* __restrict__ binned)
{
    __shared__ int cur[512];
    int b = blockIdx.x, t = threadIdx.x;
    for (int i = t; i < nb; i += 256) cur[i] = ofs[i * nblk + b];
    __syncthreads();
    int e0 = b * CH, e1 = min(E, e0 + CH);
    for (int e = e0 + t; e < e1; e += 256) {
        int row = rows[e];
        int bucket = row >> 9;
        int slot = atomicAdd(&cur[bucket], 1);
        unsigned pack = ((unsigned)(row & 511) << 23) | (unsigned)idxs[e];
        binned[slot] = make_int2((int)pack, __float_as_int(vals[e]));
    }
}

__global__ void __launch_bounds__(512) fine_scatter(
    const int2* __restrict__ binned, const int* __restrict__ ofs, int nblk, int nb,
    int E, int nrows, int* __restrict__ rowptr, int2* __restrict__ rec)
{
    __shared__ int hist[512];
    __shared__ int cur[512];
    int b = blockIdx.x, t = threadIdx.x;
    int beg = ofs[b * nblk];
    int end = (b + 1 < nb) ? ofs[(b + 1) * nblk] : E;

    hist[t] = 0;
    __syncthreads();
    for (int j = beg + t; j < end; j += 512)
        atomicAdd(&hist[((unsigned)binned[j].x) >> 23], 1);
    __syncthreads();
    int v = hist[t];
    for (int off = 1; off < 512; off <<= 1) {
        int add = (t >= off) ? hist[t - off] : 0;
        __syncthreads();
        hist[t] += add;
        __syncthreads();
    }
    int excl = hist[t] - v;
    cur[t] = excl;
    int grow = b * BROWS + t;
    if (grow <= nrows) rowptr[grow] = beg + excl;
    __syncthreads();
    for (int j = beg + t; j < end; j += 512) {
        int2 eb = binned[j];
        unsigned p = (unsigned)eb.x;
        int rl  = (int)(p >> 23);
        int idx = (int)(p & 0x7FFFFFu);
        int c = atomicAdd(&cur[rl], 1);
        rec[beg + c] = make_int2(idx, eb.y);
    }
}

__global__ void copy0_kernel(const float4* __restrict__ src, float4* __restrict__ a,
                             float4* __restrict__ b, int n4)
{
    int i = blockIdx.x * blockDim.x + threadIdx.x;
    if (i < n4) { float4 v = src[i]; a[i] = v; b[i] = v; }
}

__global__ void f2b_kernel(const float4* __restrict__ src, ushort4* __restrict__ dst, int n4)
{
    int i = blockIdx.x * blockDim.x + threadIdx.x;
    if (i < n4) {
        float4 v = src[i];
        ushort4 h;
        h.x = f2b(v.x); h.y = f2b(v.y); h.z = f2b(v.z); h.w = f2b(v.w);
        dst[i] = h;
    }
}

// ---------- Phase A: SpMM gather+reduce only, agg fp32 out ----------
struct TaskA {
    const unsigned short* gsrc;
    float* agg;
    const int* rowptr;
    const int2* recs;
    int nrows;
    int blk0;
};

__global__ void __launch_bounds__(256) spmm3(TaskA t0, TaskA t1, TaskA t2)
{
    TaskA t = (blockIdx.x >= (unsigned)t2.blk0) ? t2
            : (blockIdx.x >= (unsigned)t1.blk0) ? t1 : t0;
    int wid  = (blockIdx.x - t.blk0) * 4 + (threadIdx.x >> 6);
    int lane = threadIdx.x & 63;
    if (wid >= t.nrows) return;

    int g  = lane >> 3;   // edge sub-group 0..7
    int l8 = lane & 7;    // ushort8 slot (dims 8*l8 .. 8*l8+7)

    float a0[8], a1[8];
    #pragma unroll
    for (int m = 0; m < 8; ++m) { a0[m] = 0.f; a1[m] = 0.f; }

    int beg = t.rowptr[wid], end = t.rowptr[wid + 1];
    int j = beg + g;
    for (; j + 8 < end; j += 16) {
        int2 r0 = t.recs[j];
        int2 r1 = t.recs[j + 8];
        uint4 h0 = ((const uint4*)(t.gsrc + (size_t)r0.x * 64))[l8];
        uint4 h1 = ((const uint4*)(t.gsrc + (size_t)r1.x * 64))[l8];
        float w0 = __int_as_float(r0.y);
        float w1 = __int_as_float(r1.y);
        a0[0] += w0 * b2f_lo(h0.x); a0[1] += w0 * b2f_hi(h0.x);
        a0[2] += w0 * b2f_lo(h0.y); a0[3] += w0 * b2f_hi(h0.y);
        a0[4] += w0 * b2f_lo(h0.z); a0[5] += w0 * b2f_hi(h0.z);
        a0[6] += w0 * b2f_lo(h0.w); a0[7] += w0 * b2f_hi(h0.w);
        a1[0] += w1 * b2f_lo(h1.x); a1[1] += w1 * b2f_hi(h1.x);
        a1[2] += w1 * b2f_lo(h1.y); a1[3] += w1 * b2f_hi(h1.y);
        a1[4] += w1 * b2f_lo(h1.z); a1[5] += w1 * b2f_hi(h1.z);
        a1[6] += w1 * b2f_lo(h1.w); a1[7] += w1 * b2f_hi(h1.w);
    }
    for (; j < end; j += 8) {
        int2 r0 = t.recs[j];
        uint4 h0 = ((const uint4*)(t.gsrc + (size_t)r0.x * 64))[l8];
        float w0 = __int_as_float(r0.y);
        a0[0] += w0 * b2f_lo(h0.x); a0[1] += w0 * b2f_hi(h0.x);
        a0[2] += w0 * b2f_lo(h0.y); a0[3] += w0 * b2f_hi(h0.y);
        a0[4] += w0 * b2f_lo(h0.z); a0[5] += w0 * b2f_hi(h0.z);
        a0[6] += w0 * b2f_lo(h0.w); a0[7] += w0 * b2f_hi(h0.w);
    }
    float acc[8];
    #pragma unroll
    for (int m = 0; m < 8; ++m) acc[m] = a0[m] + a1[m];
    #pragma unroll
    for (int off = 8; off <= 32; off <<= 1)
        #pragma unroll
        for (int m = 0; m < 8; ++m)
            acc[m] += __shfl_xor(acc[m], off);

    if (g == 0) {
        float4 v0 = make_float4(acc[0], acc[1], acc[2], acc[3]);
        float4 v1 = make_float4(acc[4], acc[5], acc[6], acc[7]);
        float4* dst = (float4*)(t.agg + (size_t)wid * 64 + l8 * 8);
        dst[0] = v0;
        dst[1] = v1;
    }
}

// ---------- Phase B: dense GEMV + bias + residual + LayerNorm (persistent waves) ----------
struct TaskB {
    const float* agg;
    const float* xin;
    float* yout;
    unsigned short* youtb;
    const float* W;
    const float* bias;
    const float* gamma;
    const float* beta;
    int nrows;
    int blk0;
    int nblk;   // blocks assigned to this task
};

__global__ void __launch_bounds__(256) gemvln3(TaskB t0, TaskB t1, TaskB t2)
{
    __shared__ float Wl[64 * 64];
    __shared__ float aggL[4][64];
    TaskB t = (blockIdx.x >= (unsigned)t2.blk0) ? t2
            : (blockIdx.x >= (unsigned)t1.blk0) ? t1 : t0;
    {
        const float4* W4 = (const float4*)t.W;
        float4* Wl4 = (float4*)Wl;
        for (int i = threadIdx.x; i < 1024; i += 256) Wl4[i] = W4[i];
    }
    __syncthreads();

    int wv   = threadIdx.x >> 6;
    int lane = threadIdx.x & 63;

    // hoist W column + per-lane params into registers (amortized over ~48 rows)
    float wreg[64];
    #pragma unroll
    for (int k = 0; k < 64; ++k) wreg[k] = Wl[k * 64 + lane];
    float bia = t.bias[lane];
    float gam = t.gamma[lane];
    float bet = t.beta[lane];

    int stride = t.nblk * 4;
    for (int row = (blockIdx.x - t.blk0) * 4 + wv; row < t.nrows; row += stride) {
        float av = t.agg[(size_t)row * 64 + lane];
        float xv = t.xin[(size_t)row * 64 + lane];
        aggL[wv][lane] = av;   // same-wave write->read; no barrier needed
        float z0 = 0.f, z1 = 0.f, z2 = 0.f, z3 = 0.f;
        #pragma unroll
        for (int k = 0; k < 64; k += 4) {
            z0 += aggL[wv][k]     * wreg[k];
            z1 += aggL[wv][k + 1] * wreg[k + 1];
            z2 += aggL[wv][k + 2] * wreg[k + 2];
            z3 += aggL[wv][k + 3] * wreg[k + 3];
        }
        float tt = xv + (z0 + z1) + (z2 + z3) + bia;
        float s = tt;
        #pragma unroll
        for (int off = 32; off > 0; off >>= 1) s += __shfl_xor(s, off);
        float mean = s * (1.0f / 64.0f);
        float dv = tt - mean;
        float q2 = dv * dv;
        #pragma unroll
        for (int off = 32; off > 0; off >>= 1) q2 += __shfl_xor(q2, off);
        float var = q2 * (1.0f / 64.0f);
        float y = dv * rsqrtf(var + EPS_LN) * gam + bet;
        t.yout[(size_t)row * 64 + lane] = y;
        if (t.youtb) t.youtb[(size_t)row * 64 + lane] = f2b(y);
    }
}

extern "C" void kernel_launch(void* const* d_in, const int* in_sizes, int n_in,
                              void* d_out, int out_size, void* d_ws, size_t ws_size,
                              hipStream_t stream)
{
    const float* user_emb = (const float*)d_in[0];
    const float* item_emb = (const float*)d_in[1];
    const int*   ui_src   = (const int*)d_in[2];
    const int*   ui_dst   = (const int*)d_in[3];
    const float* ui_val   = (const float*)d_in[4];
    const int*   soc_src  = (const int*)d_in[5];
    const int*   soc_dst  = (const int*)d_in[6];
    const float* soc_val  = (const float*)d_in[7];
    const float* W_ui     = (const float*)d_in[8];
    const float* b_ui     = (const float*)d_in[9];
    const float* W_soc    = (const float*)d_in[10];
    const float* b_soc    = (const float*)d_in[11];
    const float* ln_g     = (const float*)d_in[12];
    const float* ln_b     = (const float*)d_in[13];

    float* out     = (float*)d_out;
    float* out_ui  = out;                         // [3][NU][D]
    float* out_soc = out + (size_t)3 * NU * D;    // [3][NU][D]
    float* out_it  = out + (size_t)6 * NU * D;    // [NI][D]

    const int NBU = (NU + BROWS - 1) / BROWS;     // 196
    const int NBI = (NI + BROWS - 1) / BROWS;     // 391
    const int BLK_UI  = (E_UI  + CH - 1) / CH;    // 391
    const int BLK_SOC = (E_SOC + CH - 1) / CH;    // 196

    // ---- workspace carve (256B-aligned) ----
    char* p = (char*)d_ws;
    auto take = [&](size_t bytes) { char* r = p; p += (bytes + 255) & ~(size_t)255; return r; };
    int2* rec_us = (int2*)take((size_t)E_UI * 8);
    int2* rec_ud = (int2*)take((size_t)E_UI * 8);
    int2* rec_ss = (int2*)take((size_t)E_SOC * 8);
    int2* binned = (int2*)take((size_t)E_UI * 8);      // CSR staging; = agg_u after (25.6MB exact)
    int*  rp_us  = (int*)take((size_t)(NU + 1) * 4);
    int*  rp_ud  = (int*)take((size_t)(NI + 1) * 4);
    int*  rp_ss  = (int*)take((size_t)(NU + 1) * 4);
    int*  cnt    = (int*)take((size_t)NBI * BLK_UI * 4);
    int*  ofs    = (int*)take((size_t)NBI * BLK_UI * 4);
    int*  bsum   = (int*)take(1024 * 4);
    unsigned short* u0b  = (unsigned short*)take((size_t)NU * D * 2);
    unsigned short* it0b = (unsigned short*)take((size_t)NI * D * 2);
    unsigned short* u1b  = (unsigned short*)take((size_t)NU * D * 2);
    unsigned short* s1b  = (unsigned short*)take((size_t)NU * D * 2);
    unsigned short* it1b = (unsigned short*)take((size_t)NI * D * 2);
    float* agg_i = (float*)take((size_t)NI * D * 4);   // 51.2MB
    float* agg_s = (float*)take((size_t)NU * D * 4);   // 25.6MB
    float* agg_u = (float*)binned;                     // binned dead after CSR build; NU*D*4 == E_UI*8

    auto build_csr = [&](const int* rows, const int* idxs, const float* vals,
                         int E, int nblk, int nb, int nrows, int* rowptr, int2* rec) {
        bin_count<<<nblk, 256, 0, stream>>>(rows, E, nblk, nb, cnt);
        int n = nb * nblk;
        int sb = (n + 255) / 256;
        scan_partial<<<sb, 256, 0, stream>>>(cnt, bsum, n);
        scan_bsums<<<1, 1024, 0, stream>>>(bsum, sb);
        scan_out<<<sb, 256, 0, stream>>>(cnt, bsum, ofs, n);
        bin_scatter<<<nblk, 256, 0, stream>>>(rows, idxs, vals, E, nblk, ofs, nb, binned);
        fine_scatter<<<nb, 512, 0, stream>>>(binned, ofs, nblk, nb, E, nrows, rowptr, rec);
    };

    build_csr(ui_src,  ui_dst,  ui_val,  E_UI,  BLK_UI,  NBU, NU, rp_us, rec_us);
    build_csr(ui_dst,  ui_src,  ui_val,  E_UI,  BLK_UI,  NBI, NI, rp_ud, rec_ud);
    build_csr(soc_src, soc_dst, soc_val, E_SOC, BLK_SOC, NBU, NU, rp_ss, rec_ss);

    f2b_kernel<<<(NU * 16 + 255) / 256, 256, 0, stream>>>((const float4*)user_emb,
                                                          (ushort4*)u0b, NU * 16);
    f2b_kernel<<<(NI * 16 + 255) / 256, 256, 0, stream>>>((const float4*)item_emb,
                                                          (ushort4*)it0b, NI * 16);

    int n4 = NU * D / 4;
    copy0_kernel<<<(n4 + 255) / 256, 256, 0, stream>>>((const float4*)user_emb,
                                                       (float4*)out_ui, (float4*)out_soc, n4);

    const float* u0 = user_emb;
    float* u1 = out_ui + (size_t)NU * D;
    float* u2 = out_ui + (size_t)2 * NU * D;
    const float* s0 = user_emb;
    float* s1 = out_soc + (size_t)NU * D;
    float* s2 = out_soc + (size_t)2 * NU * D;

    int ublocks = (NU + 3) / 4;   // 25000
    int iblocks = (NI + 3) / 4;   // 50000
    int agrid   = iblocks + 2 * ublocks;

    // B-phase persistent grid: proportional to rows (2:1:1)
    const int NB_I = 1040, NB_U = 520, NB_S = 520;
    int bgrid = NB_I + NB_U + NB_S;

    // ---- layer 0 ----
    {
        TaskA ai { u0b,  agg_i, rp_ud, rec_ud, NI, 0 };
        TaskA au { it0b, agg_u, rp_us, rec_us, NU, iblocks };
        TaskA as { u0b,  agg_s, rp_ss, rec_ss, NU, iblocks + ublocks };
        spmm3<<<agrid, 256, 0, stream>>>(ai, au, as);
    }
    {
        TaskB bi { agg_i, item_emb, out_it, it1b, W_ui + 0 * 4096, b_ui + 0 * 64,
                   ln_g + 1 * 64, ln_b + 1 * 64, NI, 0, NB_I };
        TaskB bu { agg_u, u0, u1, u1b, W_ui + 0 * 4096, b_ui + 0 * 64,
                   ln_g + 0 * 64, ln_b + 0 * 64, NU, NB_I, NB_U };
        TaskB bs { agg_s, s0, s1, s1b, W_soc + 0 * 4096, b_soc + 0 * 64,
                   ln_g + 0 * 64, ln_b + 0 * 64, NU, NB_I + NB_U, NB_S };
        gemvln3<<<bgrid, 256, 0, stream>>>(bi, bu, bs);
    }

    // ---- layer 1 ----
    {
        TaskA ai { u1b,  agg_i, rp_ud, rec_ud, NI, 0 };
        TaskA au { it1b, agg_u, rp_us, rec_us, NU, iblocks };
        TaskA as { s1b,  agg_s, rp_ss, rec_ss, NU, iblocks + ublocks };
        spmm3<<<agrid, 256, 0, stream>>>(ai, au, as);
    }
    {
        TaskB bi { agg_i, out_it, out_it, nullptr, W_ui + 1 * 4096, b_ui + 1 * 64,
                   ln_g + 3 * 64, ln_b + 3 * 64, NI, 0, NB_I };
        TaskB bu { agg_u, u1, u2, nullptr, W_ui + 1 * 4096, b_ui + 1 * 64,
                   ln_g + 2 * 64, ln_b + 2 * 64, NU, NB_I, NB_U };
        TaskB bs { agg_s, s1, s2, nullptr, W_soc + 1 * 4096, b_soc + 1 * 64,
                   ln_g + 2 * 64, ln_b + 2 * 64, NU, NB_I + NB_U, NB_S };
        gemvln3<<<bgrid, 256, 0, stream>>>(bi, bu, bs);
    }
}

// Round 11
// 817.136 us; speedup vs baseline: 1.7507x; 1.4495x over previous
//
#include <hip/hip_runtime.h>
#include <stdint.h>

static constexpr int NU    = 100000;
static constexpr int NI    = 200000;
static constexpr int D     = 64;
static constexpr int E_UI  = 3200000;
static constexpr int E_SOC = 1600000;
static constexpr int CH    = 8192;   // edges per binning block
static constexpr int BROWS = 512;    // rows per bucket
#define EPS_LN 1e-5f

typedef __attribute__((ext_vector_type(8))) short bf16x8;
typedef __attribute__((ext_vector_type(4))) float f32x4;

__device__ __forceinline__ unsigned short f2b(float f) {
    unsigned u = __float_as_uint(f);
    u = (u + 0x7FFFu + ((u >> 16) & 1u)) >> 16;   // RNE
    return (unsigned short)u;
}
__device__ __forceinline__ float b2fs(unsigned short h) {
    return __uint_as_float((unsigned)h << 16);
}
__device__ __forceinline__ float b2f_lo(unsigned u) { return __uint_as_float(u << 16); }
__device__ __forceinline__ float b2f_hi(unsigned u) { return __uint_as_float(u & 0xFFFF0000u); }

// ---------- CSR build (unchanged) ----------
__global__ void __launch_bounds__(256) bin_count(
    const int* __restrict__ rows, int E, int nblk, int nb, int* __restrict__ cnt)
{
    __shared__ int hist[512];
    int b = blockIdx.x, t = threadIdx.x;
    for (int i = t; i < nb; i += 256) hist[i] = 0;
    __syncthreads();
    int e0 = b * CH, e1 = min(E, e0 + CH);
    for (int e = e0 + t; e < e1; e += 256)
        atomicAdd(&hist[rows[e] >> 9], 1);
    __syncthreads();
    for (int i = t; i < nb; i += 256) cnt[i * nblk + b] = hist[i];  // bucket-major
}

__global__ void scan_partial(const int* __restrict__ cnt, int* __restrict__ bsum, int n)
{
    __shared__ int lds[256];
    int i = blockIdx.x * 256 + threadIdx.x;
    lds[threadIdx.x] = (i < n) ? cnt[i] : 0;
    __syncthreads();
    for (int off = 128; off > 0; off >>= 1) {
        if (threadIdx.x < off) lds[threadIdx.x] += lds[threadIdx.x + off];
        __syncthreads();
    }
    if (threadIdx.x == 0) bsum[blockIdx.x] = lds[0];
}

__global__ void scan_bsums(int* __restrict__ bsum, int nb)
{
    __shared__ int lds[1024];
    int t = threadIdx.x;
    int v = (t < nb) ? bsum[t] : 0;
    lds[t] = v;
    __syncthreads();
    for (int off = 1; off < 1024; off <<= 1) {
        int add = (t >= off) ? lds[t - off] : 0;
        __syncthreads();
        lds[t] += add;
        __syncthreads();
    }
    if (t < nb) bsum[t] = lds[t] - v;
}

__global__ void scan_out(const int* __restrict__ cnt, const int* __restrict__ bsum,
                         int* __restrict__ ofs, int n)
{
    __shared__ int lds[256];
    int i = blockIdx.x * 256 + threadIdx.x;
    int v = (i < n) ? cnt[i] : 0;
    lds[threadIdx.x] = v;
    __syncthreads();
    for (int off = 1; off < 256; off <<= 1) {
        int add = (threadIdx.x >= off) ? lds[threadIdx.x - off] : 0;
        __syncthreads();
        lds[threadIdx.x] += add;
        __syncthreads();
    }
    if (i < n) ofs[i] = bsum[blockIdx.x] + lds[threadIdx.x] - v;
}

__global__ void __launch_bounds__(256) bin_scatter(
    const int* __restrict__ rows, const int* __restrict__ idxs, const float* __restrict__ vals,
    int E, int nblk, const int* __restrict__ ofs, int nb, int2* __restrict__ binned)
{
    __shared__ int cur[512];
    int b = blockIdx.x, t = threadIdx.x;
    for (int i = t; i < nb; i += 256) cur[i] = ofs[i * nblk + b];
    __syncthreads();
    int e0 = b * CH, e1 = min(E, e0 + CH);
    for (int e = e0 + t; e < e1; e += 256) {
        int row = rows[e];
        int bucket = row >> 9;
        int slot = atomicAdd(&cur[bucket], 1);
        unsigned pack = ((unsigned)(row & 511) << 23) | (unsigned)idxs[e];
        binned[slot] = make_int2((int)pack, __float_as_int(vals[e]));
    }
}

__global__ void __launch_bounds__(512) fine_scatter(
    const int2* __restrict__ binned, const int* __restrict__ ofs, int nblk, int nb,
    int E, int nrows, int* __restrict__ rowptr, int2* __restrict__ rec)
{
    __shared__ int hist[512];
    __shared__ int cur[512];
    int b = blockIdx.x, t = threadIdx.x;
    int beg = ofs[b * nblk];
    int end = (b + 1 < nb) ? ofs[(b + 1) * nblk] : E;

    hist[t] = 0;
    __syncthreads();
    for (int j = beg + t; j < end; j += 512)
        atomicAdd(&hist[((unsigned)binned[j].x) >> 23], 1);
    __syncthreads();
    int v = hist[t];
    for (int off = 1; off < 512; off <<= 1) {
        int add = (t >= off) ? hist[t - off] : 0;
        __syncthreads();
        hist[t] += add;
        __syncthreads();
    }
    int excl = hist[t] - v;
    cur[t] = excl;
    int grow = b * BROWS + t;
    if (grow <= nrows) rowptr[grow] = beg + excl;
    __syncthreads();
    for (int j = beg + t; j < end; j += 512) {
        int2 eb = binned[j];
        unsigned p = (unsigned)eb.x;
        int rl  = (int)(p >> 23);
        int idx = (int)(p & 0x7FFFFFu);
        int c = atomicAdd(&cur[rl], 1);
        rec[beg + c] = make_int2(idx, eb.y);
    }
}

__global__ void copy0_kernel(const float4* __restrict__ src, float4* __restrict__ a,
                             float4* __restrict__ b, int n4)
{
    int i = blockIdx.x * blockDim.x + threadIdx.x;
    if (i < n4) { float4 v = src[i]; a[i] = v; b[i] = v; }
}

__global__ void f2b_kernel(const float4* __restrict__ src, ushort4* __restrict__ dst, int n4)
{
    int i = blockIdx.x * blockDim.x + threadIdx.x;
    if (i < n4) {
        float4 v = src[i];
        ushort4 h;
        h.x = f2b(v.x); h.y = f2b(v.y); h.z = f2b(v.z); h.w = f2b(v.w);
        dst[i] = h;
    }
}

// ---------- Phase A: SpMM gather+reduce only, agg fp32 out (unchanged) ----------
struct TaskA {
    const unsigned short* gsrc;
    float* agg;
    const int* rowptr;
    const int2* recs;
    int nrows;
    int blk0;
};

__global__ void __launch_bounds__(256) spmm3(TaskA t0, TaskA t1, TaskA t2)
{
    TaskA t = (blockIdx.x >= (unsigned)t2.blk0) ? t2
            : (blockIdx.x >= (unsigned)t1.blk0) ? t1 : t0;
    int wid  = (blockIdx.x - t.blk0) * 4 + (threadIdx.x >> 6);
    int lane = threadIdx.x & 63;
    if (wid >= t.nrows) return;

    int g  = lane >> 3;
    int l8 = lane & 7;

    float a0[8], a1[8];
    #pragma unroll
    for (int m = 0; m < 8; ++m) { a0[m] = 0.f; a1[m] = 0.f; }

    int beg = t.rowptr[wid], end = t.rowptr[wid + 1];
    int j = beg + g;
    for (; j + 8 < end; j += 16) {
        int2 r0 = t.recs[j];
        int2 r1 = t.recs[j + 8];
        uint4 h0 = ((const uint4*)(t.gsrc + (size_t)r0.x * 64))[l8];
        uint4 h1 = ((const uint4*)(t.gsrc + (size_t)r1.x * 64))[l8];
        float w0 = __int_as_float(r0.y);
        float w1 = __int_as_float(r1.y);
        a0[0] += w0 * b2f_lo(h0.x); a0[1] += w0 * b2f_hi(h0.x);
        a0[2] += w0 * b2f_lo(h0.y); a0[3] += w0 * b2f_hi(h0.y);
        a0[4] += w0 * b2f_lo(h0.z); a0[5] += w0 * b2f_hi(h0.z);
        a0[6] += w0 * b2f_lo(h0.w); a0[7] += w0 * b2f_hi(h0.w);
        a1[0] += w1 * b2f_lo(h1.x); a1[1] += w1 * b2f_hi(h1.x);
        a1[2] += w1 * b2f_lo(h1.y); a1[3] += w1 * b2f_hi(h1.y);
        a1[4] += w1 * b2f_lo(h1.z); a1[5] += w1 * b2f_hi(h1.z);
        a1[6] += w1 * b2f_lo(h1.w); a1[7] += w1 * b2f_hi(h1.w);
    }
    for (; j < end; j += 8) {
        int2 r0 = t.recs[j];
        uint4 h0 = ((const uint4*)(t.gsrc + (size_t)r0.x * 64))[l8];
        float w0 = __int_as_float(r0.y);
        a0[0] += w0 * b2f_lo(h0.x); a0[1] += w0 * b2f_hi(h0.x);
        a0[2] += w0 * b2f_lo(h0.y); a0[3] += w0 * b2f_hi(h0.y);
        a0[4] += w0 * b2f_lo(h0.z); a0[5] += w0 * b2f_hi(h0.z);
        a0[6] += w0 * b2f_lo(h0.w); a0[7] += w0 * b2f_hi(h0.w);
    }
    float acc[8];
    #pragma unroll
    for (int m = 0; m < 8; ++m) acc[m] = a0[m] + a1[m];
    #pragma unroll
    for (int off = 8; off <= 32; off <<= 1)
        #pragma unroll
        for (int m = 0; m < 8; ++m)
            acc[m] += __shfl_xor(acc[m], off);

    if (g == 0) {
        float4 v0 = make_float4(acc[0], acc[1], acc[2], acc[3]);
        float4 v1 = make_float4(acc[4], acc[5], acc[6], acc[7]);
        float4* dst = (float4*)(t.agg + (size_t)wid * 64 + l8 * 8);
        dst[0] = v0;
        dst[1] = v1;
    }
}

// ---------- Phase B: MFMA GEMM + bias + residual + LayerNorm ----------
struct TaskB {
    const float* agg;
    const float* xin;
    float* yout;
    unsigned short* youtb;
    const float* W;
    const float* bias;
    const float* gamma;
    const float* beta;
    int ntiles;  // nrows/16
    int blk0;
    int nblk;
};

__device__ __forceinline__ void split_hi_lo(const f32x4 a, const f32x4 b,
                                            bf16x8& hi, bf16x8& lo)
{
    #pragma unroll
    for (int j = 0; j < 4; ++j) {
        unsigned short h = f2b(a[j]);
        hi[j] = (short)h;
        lo[j] = (short)f2b(a[j] - b2fs(h));
    }
    #pragma unroll
    for (int j = 0; j < 4; ++j) {
        unsigned short h = f2b(b[j]);
        hi[4 + j] = (short)h;
        lo[4 + j] = (short)f2b(b[j] - b2fs(h));
    }
}

__global__ void __launch_bounds__(256) gemmln3(TaskB t0, TaskB t1, TaskB t2)
{
    __shared__ float Wl[64 * 64];
    TaskB t = (blockIdx.x >= (unsigned)t2.blk0) ? t2
            : (blockIdx.x >= (unsigned)t1.blk0) ? t1 : t0;
    {
        const float4* W4 = (const float4*)t.W;
        float4* Wl4 = (float4*)Wl;
        for (int i = threadIdx.x; i < 1024; i += 256) Wl4[i] = W4[i];
    }
    __syncthreads();

    int wv   = threadIdx.x >> 6;
    int lane = threadIdx.x & 63;
    int g    = lane >> 4;    // 16-lane group 0..3
    int c    = lane & 15;

    // B-fragments of W (hi/lo), built once: W[k][n], k = kt*32+8g+j, n = nt*16+c
    bf16x8 Whi[2][4], Wlo[2][4];
    #pragma unroll
    for (int kt = 0; kt < 2; ++kt)
        #pragma unroll
        for (int nt = 0; nt < 4; ++nt) {
            #pragma unroll
            for (int j = 0; j < 8; ++j) {
                float w = Wl[(kt * 32 + 8 * g + j) * 64 + nt * 16 + c];
                unsigned short h = f2b(w);
                Whi[kt][nt][j] = (short)h;
                Wlo[kt][nt][j] = (short)f2b(w - b2fs(h));
            }
        }
    float bia[4], gam[4], bet[4];
    #pragma unroll
    for (int nt = 0; nt < 4; ++nt) {
        bia[nt] = t.bias[nt * 16 + c];
        gam[nt] = t.gamma[nt * 16 + c];
        bet[nt] = t.beta[nt * 16 + c];
    }

    int stride = t.nblk * 4;
    for (int tile = (blockIdx.x - t.blk0) * 4 + wv; tile < t.ntiles; tile += stride) {
        int rowbase = tile * 16;
        // A-fragments: row = rowbase + c, k = kt*32 + 8g + j  (8 contiguous fp32)
        const float* arow = t.agg + (size_t)(rowbase + c) * 64 + 8 * g;
        f32x4 a00 = *(const f32x4*)(arow);
        f32x4 a01 = *(const f32x4*)(arow + 4);
        f32x4 a10 = *(const f32x4*)(arow + 32);
        f32x4 a11 = *(const f32x4*)(arow + 36);
        bf16x8 Ahi0, Alo0, Ahi1, Alo1;
        split_hi_lo(a00, a01, Ahi0, Alo0);
        split_hi_lo(a10, a11, Ahi1, Alo1);

        f32x4 acc[4];
        #pragma unroll
        for (int nt = 0; nt < 4; ++nt) {
            f32x4 z = {0.f, 0.f, 0.f, 0.f};
            z = __builtin_amdgcn_mfma_f32_16x16x32_bf16(Ahi0, Whi[0][nt], z, 0, 0, 0);
            z = __builtin_amdgcn_mfma_f32_16x16x32_bf16(Ahi1, Whi[1][nt], z, 0, 0, 0);
            z = __builtin_amdgcn_mfma_f32_16x16x32_bf16(Alo0, Whi[0][nt], z, 0, 0, 0);
            z = __builtin_amdgcn_mfma_f32_16x16x32_bf16(Alo1, Whi[1][nt], z, 0, 0, 0);
            z = __builtin_amdgcn_mfma_f32_16x16x32_bf16(Ahi0, Wlo[0][nt], z, 0, 0, 0);
            z = __builtin_amdgcn_mfma_f32_16x16x32_bf16(Ahi1, Wlo[1][nt], z, 0, 0, 0);
            acc[nt] = z;
        }

        // C layout: row = rowbase + 4g + reg, col = nt*16 + c
        float tv[4][4];   // [nt][reg]
        #pragma unroll
        for (int reg = 0; reg < 4; ++reg) {
            int row = rowbase + 4 * g + reg;
            const float* xrow = t.xin + (size_t)row * 64 + c;
            #pragma unroll
            for (int nt = 0; nt < 4; ++nt)
                tv[nt][reg] = acc[nt][reg] + bia[nt] + xrow[nt * 16];
        }
        // LayerNorm per row (rows live in 16-lane groups; reduce via xor 1,2,4,8)
        #pragma unroll
        for (int reg = 0; reg < 4; ++reg) {
            float s = tv[0][reg] + tv[1][reg] + tv[2][reg] + tv[3][reg];
            #pragma unroll
            for (int off = 1; off <= 8; off <<= 1) s += __shfl_xor(s, off);
            float mean = s * (1.0f / 64.0f);
            float q = 0.f;
            #pragma unroll
            for (int nt = 0; nt < 4; ++nt) {
                float dv = tv[nt][reg] - mean;
                q += dv * dv;
            }
            #pragma unroll
            for (int off = 1; off <= 8; off <<= 1) q += __shfl_xor(q, off);
            float rs = rsqrtf(q * (1.0f / 64.0f) + EPS_LN);
            int row = rowbase + 4 * g + reg;
            float* yrow = t.yout + (size_t)row * 64 + c;
            #pragma unroll
            for (int nt = 0; nt < 4; ++nt) {
                float y = (tv[nt][reg] - mean) * rs * gam[nt] + bet[nt];
                yrow[nt * 16] = y;
                if (t.youtb) t.youtb[(size_t)row * 64 + nt * 16 + c] = f2b(y);
            }
        }
    }
}

extern "C" void kernel_launch(void* const* d_in, const int* in_sizes, int n_in,
                              void* d_out, int out_size, void* d_ws, size_t ws_size,
                              hipStream_t stream)
{
    const float* user_emb = (const float*)d_in[0];
    const float* item_emb = (const float*)d_in[1];
    const int*   ui_src   = (const int*)d_in[2];
    const int*   ui_dst   = (const int*)d_in[3];
    const float* ui_val   = (const float*)d_in[4];
    const int*   soc_src  = (const int*)d_in[5];
    const int*   soc_dst  = (const int*)d_in[6];
    const float* soc_val  = (const float*)d_in[7];
    const float* W_ui     = (const float*)d_in[8];
    const float* b_ui     = (const float*)d_in[9];
    const float* W_soc    = (const float*)d_in[10];
    const float* b_soc    = (const float*)d_in[11];
    const float* ln_g     = (const float*)d_in[12];
    const float* ln_b     = (const float*)d_in[13];

    float* out     = (float*)d_out;
    float* out_ui  = out;                         // [3][NU][D]
    float* out_soc = out + (size_t)3 * NU * D;    // [3][NU][D]
    float* out_it  = out + (size_t)6 * NU * D;    // [NI][D]

    const int NBU = (NU + BROWS - 1) / BROWS;     // 196
    const int NBI = (NI + BROWS - 1) / BROWS;     // 391
    const int BLK_UI  = (E_UI  + CH - 1) / CH;    // 391
    const int BLK_SOC = (E_SOC + CH - 1) / CH;    // 196

    // ---- workspace carve (256B-aligned) ----
    char* p = (char*)d_ws;
    auto take = [&](size_t bytes) { char* r = p; p += (bytes + 255) & ~(size_t)255; return r; };
    int2* rec_us = (int2*)take((size_t)E_UI * 8);
    int2* rec_ud = (int2*)take((size_t)E_UI * 8);
    int2* rec_ss = (int2*)take((size_t)E_SOC * 8);
    int2* binned = (int2*)take((size_t)E_UI * 8);      // CSR staging; = agg_u after
    int*  rp_us  = (int*)take((size_t)(NU + 1) * 4);
    int*  rp_ud  = (int*)take((size_t)(NI + 1) * 4);
    int*  rp_ss  = (int*)take((size_t)(NU + 1) * 4);
    int*  cnt    = (int*)take((size_t)NBI * BLK_UI * 4);
    int*  ofs    = (int*)take((size_t)NBI * BLK_UI * 4);
    int*  bsum   = (int*)take(1024 * 4);
    unsigned short* u0b  = (unsigned short*)take((size_t)NU * D * 2);
    unsigned short* it0b = (unsigned short*)take((size_t)NI * D * 2);
    unsigned short* u1b  = (unsigned short*)take((size_t)NU * D * 2);
    unsigned short* s1b  = (unsigned short*)take((size_t)NU * D * 2);
    unsigned short* it1b = (unsigned short*)take((size_t)NI * D * 2);
    float* agg_i = (float*)take((size_t)NI * D * 4);
    float* agg_s = (float*)take((size_t)NU * D * 4);
    float* agg_u = (float*)binned;                     // binned dead after CSR build

    auto build_csr = [&](const int* rows, const int* idxs, const float* vals,
                         int E, int nblk, int nb, int nrows, int* rowptr, int2* rec) {
        bin_count<<<nblk, 256, 0, stream>>>(rows, E, nblk, nb, cnt);
        int n = nb * nblk;
        int sb = (n + 255) / 256;
        scan_partial<<<sb, 256, 0, stream>>>(cnt, bsum, n);
        scan_bsums<<<1, 1024, 0, stream>>>(bsum, sb);
        scan_out<<<sb, 256, 0, stream>>>(cnt, bsum, ofs, n);
        bin_scatter<<<nblk, 256, 0, stream>>>(rows, idxs, vals, E, nblk, ofs, nb, binned);
        fine_scatter<<<nb, 512, 0, stream>>>(binned, ofs, nblk, nb, E, nrows, rowptr, rec);
    };

    build_csr(ui_src,  ui_dst,  ui_val,  E_UI,  BLK_UI,  NBU, NU, rp_us, rec_us);
    build_csr(ui_dst,  ui_src,  ui_val,  E_UI,  BLK_UI,  NBI, NI, rp_ud, rec_ud);
    build_csr(soc_src, soc_dst, soc_val, E_SOC, BLK_SOC, NBU, NU, rp_ss, rec_ss);

    f2b_kernel<<<(NU * 16 + 255) / 256, 256, 0, stream>>>((const float4*)user_emb,
                                                          (ushort4*)u0b, NU * 16);
    f2b_kernel<<<(NI * 16 + 255) / 256, 256, 0, stream>>>((const float4*)item_emb,
                                                          (ushort4*)it0b, NI * 16);

    int n4 = NU * D / 4;
    copy0_kernel<<<(n4 + 255) / 256, 256, 0, stream>>>((const float4*)user_emb,
                                                       (float4*)out_ui, (float4*)out_soc, n4);

    const float* u0 = user_emb;
    float* u1 = out_ui + (size_t)NU * D;
    float* u2 = out_ui + (size_t)2 * NU * D;
    const float* s0 = user_emb;
    float* s1 = out_soc + (size_t)NU * D;
    float* s2 = out_soc + (size_t)2 * NU * D;

    int ublocks = (NU + 3) / 4;   // 25000
    int iblocks = (NI + 3) / 4;   // 50000
    int agrid   = iblocks + 2 * ublocks;

    const int NB_I = 1040, NB_U = 520, NB_S = 520;
    int bgrid = NB_I + NB_U + NB_S;
    const int TIL_I = NI / 16, TIL_U = NU / 16;   // 12500, 6250 (both exact)

    // ---- layer 0 ----
    {
        TaskA ai { u0b,  agg_i, rp_ud, rec_ud, NI, 0 };
        TaskA au { it0b, agg_u, rp_us, rec_us, NU, iblocks };
        TaskA as { u0b,  agg_s, rp_ss, rec_ss, NU, iblocks + ublocks };
        spmm3<<<agrid, 256, 0, stream>>>(ai, au, as);
    }
    {
        TaskB bi { agg_i, item_emb, out_it, it1b, W_ui + 0 * 4096, b_ui + 0 * 64,
                   ln_g + 1 * 64, ln_b + 1 * 64, TIL_I, 0, NB_I };
        TaskB bu { agg_u, u0, u1, u1b, W_ui + 0 * 4096, b_ui + 0 * 64,
                   ln_g + 0 * 64, ln_b + 0 * 64, TIL_U, NB_I, NB_U };
        TaskB bs { agg_s, s0, s1, s1b, W_soc + 0 * 4096, b_soc + 0 * 64,
                   ln_g + 0 * 64, ln_b + 0 * 64, TIL_U, NB_I + NB_U, NB_S };
        gemmln3<<<bgrid, 256, 0, stream>>>(bi, bu, bs);
    }

    // ---- layer 1 ----
    {
        TaskA ai { u1b,  agg_i, rp_ud, rec_ud, NI, 0 };
        TaskA au { it1b, agg_u, rp_us, rec_us, NU, iblocks };
        TaskA as { s1b,  agg_s, rp_ss, rec_ss, NU, iblocks + ublocks };
        spmm3<<<agrid, 256, 0, stream>>>(ai, au, as);
    }
    {
        TaskB bi { agg_i, out_it, out_it, nullptr, W_ui + 1 * 4096, b_ui + 1 * 64,
                   ln_g + 3 * 64, ln_b + 3 * 64, TIL_I, 0, NB_I };
        TaskB bu { agg_u, u1, u2, nullptr, W_ui + 1 * 4096, b_ui + 1 * 64,
                   ln_g + 2 * 64, ln_b + 2 * 64, TIL_U, NB_I, NB_U };
        TaskB bs { agg_s, s1, s2, nullptr, W_soc + 1 * 4096, b_soc + 1 * 64,
                   ln_g + 2 * 64, ln_b + 2 * 64, TIL_U, NB_I + NB_U, NB_S };
        gemmln3<<<bgrid, 256, 0, stream>>>(bi, bu, bs);
    }
}

// Round 12
// 812.630 us; speedup vs baseline: 1.7605x; 1.0055x over previous
//
#include <hip/hip_runtime.h>
#include <stdint.h>

static constexpr int NU    = 100000;
static constexpr int NI    = 200000;
static constexpr int D     = 64;
static constexpr int E_UI  = 3200000;
static constexpr int E_SOC = 1600000;
static constexpr int CH    = 8192;   // edges per binning block
static constexpr int BROWS = 512;    // rows per bucket
#define EPS_LN 1e-5f

typedef __attribute__((ext_vector_type(8))) short bf16x8;
typedef __attribute__((ext_vector_type(4))) float f32x4;

__device__ __forceinline__ unsigned short f2b(float f) {
    unsigned u = __float_as_uint(f);
    u = (u + 0x7FFFu + ((u >> 16) & 1u)) >> 16;   // RNE
    return (unsigned short)u;
}
__device__ __forceinline__ float b2fs(unsigned short h) {
    return __uint_as_float((unsigned)h << 16);
}
__device__ __forceinline__ float b2f_lo(unsigned u) { return __uint_as_float(u << 16); }
__device__ __forceinline__ float b2f_hi(unsigned u) { return __uint_as_float(u & 0xFFFF0000u); }

// ---------- CSR build (unchanged) ----------
__global__ void __launch_bounds__(256) bin_count(
    const int* __restrict__ rows, int E, int nblk, int nb, int* __restrict__ cnt)
{
    __shared__ int hist[512];
    int b = blockIdx.x, t = threadIdx.x;
    for (int i = t; i < nb; i += 256) hist[i] = 0;
    __syncthreads();
    int e0 = b * CH, e1 = min(E, e0 + CH);
    for (int e = e0 + t; e < e1; e += 256)
        atomicAdd(&hist[rows[e] >> 9], 1);
    __syncthreads();
    for (int i = t; i < nb; i += 256) cnt[i * nblk + b] = hist[i];  // bucket-major
}

__global__ void scan_partial(const int* __restrict__ cnt, int* __restrict__ bsum, int n)
{
    __shared__ int lds[256];
    int i = blockIdx.x * 256 + threadIdx.x;
    lds[threadIdx.x] = (i < n) ? cnt[i] : 0;
    __syncthreads();
    for (int off = 128; off > 0; off >>= 1) {
        if (threadIdx.x < off) lds[threadIdx.x] += lds[threadIdx.x + off];
        __syncthreads();
    }
    if (threadIdx.x == 0) bsum[blockIdx.x] = lds[0];
}

__global__ void scan_bsums(int* __restrict__ bsum, int nb)
{
    __shared__ int lds[1024];
    int t = threadIdx.x;
    int v = (t < nb) ? bsum[t] : 0;
    lds[t] = v;
    __syncthreads();
    for (int off = 1; off < 1024; off <<= 1) {
        int add = (t >= off) ? lds[t - off] : 0;
        __syncthreads();
        lds[t] += add;
        __syncthreads();
    }
    if (t < nb) bsum[t] = lds[t] - v;
}

__global__ void scan_out(const int* __restrict__ cnt, const int* __restrict__ bsum,
                         int* __restrict__ ofs, int n)
{
    __shared__ int lds[256];
    int i = blockIdx.x * 256 + threadIdx.x;
    int v = (i < n) ? cnt[i] : 0;
    lds[threadIdx.x] = v;
    __syncthreads();
    for (int off = 1; off < 256; off <<= 1) {
        int add = (threadIdx.x >= off) ? lds[threadIdx.x - off] : 0;
        __syncthreads();
        lds[threadIdx.x] += add;
        __syncthreads();
    }
    if (i < n) ofs[i] = bsum[blockIdx.x] + lds[threadIdx.x] - v;
}

__global__ void __launch_bounds__(256) bin_scatter(
    const int* __restrict__ rows, const int* __restrict__ idxs, const float* __restrict__ vals,
    int E, int nblk, const int* __restrict__ ofs, int nb, int2* __restrict__ binned)
{
    __shared__ int cur[512];
    int b = blockIdx.x, t = threadIdx.x;
    for (int i = t; i < nb; i += 256) cur[i] = ofs[i * nblk + b];
    __syncthreads();
    int e0 = b * CH, e1 = min(E, e0 + CH);
    for (int e = e0 + t; e < e1; e += 256) {
        int row = rows[e];
        int bucket = row >> 9;
        int slot = atomicAdd(&cur[bucket], 1);
        unsigned pack = ((unsigned)(row & 511) << 23) | (unsigned)idxs[e];
        binned[slot] = make_int2((int)pack, __float_as_int(vals[e]));
    }
}

__global__ void __launch_bounds__(512) fine_scatter(
    const int2* __restrict__ binned, const int* __restrict__ ofs, int nblk, int nb,
    int E, int nrows, int* __restrict__ rowptr, int2* __restrict__ rec)
{
    __shared__ int hist[512];
    __shared__ int cur[512];
    int b = blockIdx.x, t = threadIdx.x;
    int beg = ofs[b * nblk];
    int end = (b + 1 < nb) ? ofs[(b + 1) * nblk] : E;

    hist[t] = 0;
    __syncthreads();
    for (int j = beg + t; j < end; j += 512)
        atomicAdd(&hist[((unsigned)binned[j].x) >> 23], 1);
    __syncthreads();
    int v = hist[t];
    for (int off = 1; off < 512; off <<= 1) {
        int add = (t >= off) ? hist[t - off] : 0;
        __syncthreads();
        hist[t] += add;
        __syncthreads();
    }
    int excl = hist[t] - v;
    cur[t] = excl;
    int grow = b * BROWS + t;
    if (grow <= nrows) rowptr[grow] = beg + excl;
    __syncthreads();
    for (int j = beg + t; j < end; j += 512) {
        int2 eb = binned[j];
        unsigned p = (unsigned)eb.x;
        int rl  = (int)(p >> 23);
        int idx = (int)(p & 0x7FFFFFu);
        int c = atomicAdd(&cur[rl], 1);
        rec[beg + c] = make_int2(idx, eb.y);
    }
}

__global__ void copy0_kernel(const float4* __restrict__ src, float4* __restrict__ a,
                             float4* __restrict__ b, int n4)
{
    int i = blockIdx.x * blockDim.x + threadIdx.x;
    if (i < n4) { float4 v = src[i]; a[i] = v; b[i] = v; }
}

// ---------- table GEMM: tab = bf16(X @ W), MFMA hi/lo split ----------
struct TaskT {
    const float* x;
    unsigned short* tab;
    const float* W;
    int ntiles;   // nrows/16
    int blk0;
    int nblk;
};

__device__ __forceinline__ void split_hi_lo(const f32x4 a, const f32x4 b,
                                            bf16x8& hi, bf16x8& lo)
{
    #pragma unroll
    for (int j = 0; j < 4; ++j) {
        unsigned short h = f2b(a[j]);
        hi[j] = (short)h;
        lo[j] = (short)f2b(a[j] - b2fs(h));
    }
    #pragma unroll
    for (int j = 0; j < 4; ++j) {
        unsigned short h = f2b(b[j]);
        hi[4 + j] = (short)h;
        lo[4 + j] = (short)f2b(b[j] - b2fs(h));
    }
}

__global__ void __launch_bounds__(256) btab3(TaskT t0, TaskT t1, TaskT t2)
{
    __shared__ float Wl[64 * 64];
    TaskT t = (blockIdx.x >= (unsigned)t2.blk0) ? t2
            : (blockIdx.x >= (unsigned)t1.blk0) ? t1 : t0;
    {
        const float4* W4 = (const float4*)t.W;
        float4* Wl4 = (float4*)Wl;
        for (int i = threadIdx.x; i < 1024; i += 256) Wl4[i] = W4[i];
    }
    __syncthreads();

    int wv   = threadIdx.x >> 6;
    int lane = threadIdx.x & 63;
    int g    = lane >> 4;
    int c    = lane & 15;

    // W fragments: k = kt*32 + 8g + j, n = nt*16 + c
    bf16x8 Whi[2][4], Wlo[2][4];
    #pragma unroll
    for (int kt = 0; kt < 2; ++kt)
        #pragma unroll
        for (int nt = 0; nt < 4; ++nt)
            #pragma unroll
            for (int j = 0; j < 8; ++j) {
                float w = Wl[(kt * 32 + 8 * g + j) * 64 + nt * 16 + c];
                unsigned short h = f2b(w);
                Whi[kt][nt][j] = (short)h;
                Wlo[kt][nt][j] = (short)f2b(w - b2fs(h));
            }

    int stride = t.nblk * 4;
    for (int tile = (blockIdx.x - t.blk0) * 4 + wv; tile < t.ntiles; tile += stride) {
        int rowbase = tile * 16;
        const float* arow = t.x + (size_t)(rowbase + c) * 64 + 8 * g;
        f32x4 a00 = *(const f32x4*)(arow);
        f32x4 a01 = *(const f32x4*)(arow + 4);
        f32x4 a10 = *(const f32x4*)(arow + 32);
        f32x4 a11 = *(const f32x4*)(arow + 36);
        bf16x8 Ahi0, Alo0, Ahi1, Alo1;
        split_hi_lo(a00, a01, Ahi0, Alo0);
        split_hi_lo(a10, a11, Ahi1, Alo1);

        #pragma unroll
        for (int nt = 0; nt < 4; ++nt) {
            f32x4 z = {0.f, 0.f, 0.f, 0.f};
            z = __builtin_amdgcn_mfma_f32_16x16x32_bf16(Ahi0, Whi[0][nt], z, 0, 0, 0);
            z = __builtin_amdgcn_mfma_f32_16x16x32_bf16(Ahi1, Whi[1][nt], z, 0, 0, 0);
            z = __builtin_amdgcn_mfma_f32_16x16x32_bf16(Alo0, Whi[0][nt], z, 0, 0, 0);
            z = __builtin_amdgcn_mfma_f32_16x16x32_bf16(Alo1, Whi[1][nt], z, 0, 0, 0);
            z = __builtin_amdgcn_mfma_f32_16x16x32_bf16(Ahi0, Wlo[0][nt], z, 0, 0, 0);
            z = __builtin_amdgcn_mfma_f32_16x16x32_bf16(Ahi1, Wlo[1][nt], z, 0, 0, 0);
            // C: row = rowbase + 4g + reg, col = nt*16 + c
            #pragma unroll
            for (int reg = 0; reg < 4; ++reg)
                t.tab[(size_t)(rowbase + 4 * g + reg) * 64 + nt * 16 + c] = f2b(z[reg]);
        }
    }
}

// ---------- fused SpMM(gather pre-transformed table) + bias + residual + LN ----------
struct TaskS {
    const unsigned short* gsrc;   // bf16 table = X @ W
    const float* xin;
    float* yout;
    const int* rowptr;
    const int2* recs;
    const float* bias;
    const float* gamma;
    const float* beta;
    int nrows;
    int blk0;
};

__global__ void __launch_bounds__(256) spmmln3(TaskS t0, TaskS t1, TaskS t2)
{
    TaskS t = (blockIdx.x >= (unsigned)t2.blk0) ? t2
            : (blockIdx.x >= (unsigned)t1.blk0) ? t1 : t0;
    int wid  = (blockIdx.x - t.blk0) * 4 + (threadIdx.x >> 6);
    int lane = threadIdx.x & 63;
    if (wid >= t.nrows) return;

    int g  = lane >> 3;   // edge sub-group 0..7
    int l8 = lane & 7;    // ushort8 slot (dims 8*l8 .. 8*l8+7)

    float a0[8], a1[8];
    #pragma unroll
    for (int m = 0; m < 8; ++m) { a0[m] = 0.f; a1[m] = 0.f; }

    int beg = t.rowptr[wid], end = t.rowptr[wid + 1];
    int j = beg + g;
    for (; j + 8 < end; j += 16) {
        int2 r0 = t.recs[j];
        int2 r1 = t.recs[j + 8];
        uint4 h0 = ((const uint4*)(t.gsrc + (size_t)r0.x * 64))[l8];
        uint4 h1 = ((const uint4*)(t.gsrc + (size_t)r1.x * 64))[l8];
        float w0 = __int_as_float(r0.y);
        float w1 = __int_as_float(r1.y);
        a0[0] += w0 * b2f_lo(h0.x); a0[1] += w0 * b2f_hi(h0.x);
        a0[2] += w0 * b2f_lo(h0.y); a0[3] += w0 * b2f_hi(h0.y);
        a0[4] += w0 * b2f_lo(h0.z); a0[5] += w0 * b2f_hi(h0.z);
        a0[6] += w0 * b2f_lo(h0.w); a0[7] += w0 * b2f_hi(h0.w);
        a1[0] += w1 * b2f_lo(h1.x); a1[1] += w1 * b2f_hi(h1.x);
        a1[2] += w1 * b2f_lo(h1.y); a1[3] += w1 * b2f_hi(h1.y);
        a1[4] += w1 * b2f_lo(h1.z); a1[5] += w1 * b2f_hi(h1.z);
        a1[6] += w1 * b2f_lo(h1.w); a1[7] += w1 * b2f_hi(h1.w);
    }
    for (; j < end; j += 8) {
        int2 r0 = t.recs[j];
        uint4 h0 = ((const uint4*)(t.gsrc + (size_t)r0.x * 64))[l8];
        float w0 = __int_as_float(r0.y);
        a0[0] += w0 * b2f_lo(h0.x); a0[1] += w0 * b2f_hi(h0.x);
        a0[2] += w0 * b2f_lo(h0.y); a0[3] += w0 * b2f_hi(h0.y);
        a0[4] += w0 * b2f_lo(h0.z); a0[5] += w0 * b2f_hi(h0.z);
        a0[6] += w0 * b2f_lo(h0.w); a0[7] += w0 * b2f_hi(h0.w);
    }
    float acc[8];
    #pragma unroll
    for (int m = 0; m < 8; ++m) acc[m] = a0[m] + a1[m];
    #pragma unroll
    for (int off = 8; off <= 32; off <<= 1)
        #pragma unroll
        for (int m = 0; m < 8; ++m)
            acc[m] += __shfl_xor(acc[m], off);
    // all lanes hold acc for dims 8*l8+m (replicated across g)

    // residual + bias + LayerNorm
    const float4* xi = (const float4*)(t.xin + (size_t)wid * 64 + 8 * l8);
    const float4* bi = (const float4*)(t.bias + 8 * l8);
    float4 x0 = xi[0], x1 = xi[1];
    float4 bb0 = bi[0], bb1 = bi[1];
    float tv[8];
    tv[0] = x0.x + acc[0] + bb0.x; tv[1] = x0.y + acc[1] + bb0.y;
    tv[2] = x0.z + acc[2] + bb0.z; tv[3] = x0.w + acc[3] + bb0.w;
    tv[4] = x1.x + acc[4] + bb1.x; tv[5] = x1.y + acc[5] + bb1.y;
    tv[6] = x1.z + acc[6] + bb1.z; tv[7] = x1.w + acc[7] + bb1.w;

    float s = 0.f;
    #pragma unroll
    for (int m = 0; m < 8; ++m) s += tv[m];
    #pragma unroll
    for (int off = 1; off <= 4; off <<= 1) s += __shfl_xor(s, off);
    float mean = s * (1.0f / 64.0f);
    float q = 0.f;
    #pragma unroll
    for (int m = 0; m < 8; ++m) { float dv = tv[m] - mean; q += dv * dv; }
    #pragma unroll
    for (int off = 1; off <= 4; off <<= 1) q += __shfl_xor(q, off);
    float rs = rsqrtf(q * (1.0f / 64.0f) + EPS_LN);

    if (g == 0) {
        const float4* ga = (const float4*)(t.gamma + 8 * l8);
        const float4* be = (const float4*)(t.beta + 8 * l8);
        float4 g0 = ga[0], g1 = ga[1];
        float4 e0 = be[0], e1 = be[1];
        float4 y0, y1;
        y0.x = (tv[0] - mean) * rs * g0.x + e0.x;
        y0.y = (tv[1] - mean) * rs * g0.y + e0.y;
        y0.z = (tv[2] - mean) * rs * g0.z + e0.z;
        y0.w = (tv[3] - mean) * rs * g0.w + e0.w;
        y1.x = (tv[4] - mean) * rs * g1.x + e1.x;
        y1.y = (tv[5] - mean) * rs * g1.y + e1.y;
        y1.z = (tv[6] - mean) * rs * g1.z + e1.z;
        y1.w = (tv[7] - mean) * rs * g1.w + e1.w;
        float4* yo = (float4*)(t.yout + (size_t)wid * 64 + 8 * l8);
        yo[0] = y0;
        yo[1] = y1;
    }
}

extern "C" void kernel_launch(void* const* d_in, const int* in_sizes, int n_in,
                              void* d_out, int out_size, void* d_ws, size_t ws_size,
                              hipStream_t stream)
{
    const float* user_emb = (const float*)d_in[0];
    const float* item_emb = (const float*)d_in[1];
    const int*   ui_src   = (const int*)d_in[2];
    const int*   ui_dst   = (const int*)d_in[3];
    const float* ui_val   = (const float*)d_in[4];
    const int*   soc_src  = (const int*)d_in[5];
    const int*   soc_dst  = (const int*)d_in[6];
    const float* soc_val  = (const float*)d_in[7];
    const float* W_ui     = (const float*)d_in[8];
    const float* b_ui     = (const float*)d_in[9];
    const float* W_soc    = (const float*)d_in[10];
    const float* b_soc    = (const float*)d_in[11];
    const float* ln_g     = (const float*)d_in[12];
    const float* ln_b     = (const float*)d_in[13];

    float* out     = (float*)d_out;
    float* out_ui  = out;                         // [3][NU][D]
    float* out_soc = out + (size_t)3 * NU * D;    // [3][NU][D]
    float* out_it  = out + (size_t)6 * NU * D;    // [NI][D]

    const int NBU = (NU + BROWS - 1) / BROWS;     // 196
    const int NBI = (NI + BROWS - 1) / BROWS;     // 391
    const int BLK_UI  = (E_UI  + CH - 1) / CH;    // 391
    const int BLK_SOC = (E_SOC + CH - 1) / CH;    // 196

    // ---- workspace carve (256B-aligned) ----
    char* p = (char*)d_ws;
    auto take = [&](size_t bytes) { char* r = p; p += (bytes + 255) & ~(size_t)255; return r; };
    int2* rec_us = (int2*)take((size_t)E_UI * 8);
    int2* rec_ud = (int2*)take((size_t)E_UI * 8);
    int2* rec_ss = (int2*)take((size_t)E_SOC * 8);
    int2* binned = (int2*)take((size_t)E_UI * 8);      // CSR staging; = twu after (25.6MB exact)
    int*  rp_us  = (int*)take((size_t)(NU + 1) * 4);
    int*  rp_ud  = (int*)take((size_t)(NI + 1) * 4);
    int*  rp_ss  = (int*)take((size_t)(NU + 1) * 4);
    int*  cnt    = (int*)take((size_t)NBI * BLK_UI * 4);
    int*  ofs    = (int*)take((size_t)NBI * BLK_UI * 4);
    int*  bsum   = (int*)take(1024 * 4);
    unsigned short* twi = (unsigned short*)take((size_t)NU * D * 2);  // u_cur @ W_ui   (item update)
    unsigned short* tws = (unsigned short*)take((size_t)NU * D * 2);  // s_cur @ W_soc  (social update)
    unsigned short* twu = (unsigned short*)binned;                    // it_cur @ W_ui  (user update), NI rows

    auto build_csr = [&](const int* rows, const int* idxs, const float* vals,
                         int E, int nblk, int nb, int nrows, int* rowptr, int2* rec) {
        bin_count<<<nblk, 256, 0, stream>>>(rows, E, nblk, nb, cnt);
        int n = nb * nblk;
        int sb = (n + 255) / 256;
        scan_partial<<<sb, 256, 0, stream>>>(cnt, bsum, n);
        scan_bsums<<<1, 1024, 0, stream>>>(bsum, sb);
        scan_out<<<sb, 256, 0, stream>>>(cnt, bsum, ofs, n);
        bin_scatter<<<nblk, 256, 0, stream>>>(rows, idxs, vals, E, nblk, ofs, nb, binned);
        fine_scatter<<<nb, 512, 0, stream>>>(binned, ofs, nblk, nb, E, nrows, rowptr, rec);
    };

    build_csr(ui_src,  ui_dst,  ui_val,  E_UI,  BLK_UI,  NBU, NU, rp_us, rec_us);
    build_csr(ui_dst,  ui_src,  ui_val,  E_UI,  BLK_UI,  NBI, NI, rp_ud, rec_ud);
    build_csr(soc_src, soc_dst, soc_val, E_SOC, BLK_SOC, NBU, NU, rp_ss, rec_ss);

    int n4 = NU * D / 4;
    copy0_kernel<<<(n4 + 255) / 256, 256, 0, stream>>>((const float4*)user_emb,
                                                       (float4*)out_ui, (float4*)out_soc, n4);

    const float* u0 = user_emb;
    float* u1 = out_ui + (size_t)NU * D;
    float* u2 = out_ui + (size_t)2 * NU * D;
    const float* s0 = user_emb;
    float* s1 = out_soc + (size_t)NU * D;
    float* s2 = out_soc + (size_t)2 * NU * D;

    int ublocks = (NU + 3) / 4;   // 25000
    int iblocks = (NI + 3) / 4;   // 50000
    int agrid   = iblocks + 2 * ublocks;

    const int TB_I = 1040, TB_U = 520, TB_S = 520;   // btab3 persistent grid split
    int tgrid = TB_I + TB_U + TB_S;
    const int TIL_I = NI / 16, TIL_U = NU / 16;      // 12500, 6250 (exact)

    // ---- layer 0 ----
    {
        // twu = it0 @ W_ui[0] (NI rows); twi = u0 @ W_ui[0]; tws = u0 @ W_soc[0]
        TaskT ta { item_emb, twu, W_ui + 0 * 4096, TIL_I, 0, TB_I };
        TaskT tb { u0,       twi, W_ui + 0 * 4096, TIL_U, TB_I, TB_U };
        TaskT tc { u0,       tws, W_soc + 0 * 4096, TIL_U, TB_I + TB_U, TB_S };
        btab3<<<tgrid, 256, 0, stream>>>(ta, tb, tc);
    }
    {
        TaskS si { twi, item_emb, out_it, rp_ud, rec_ud, b_ui + 0 * 64,
                   ln_g + 1 * 64, ln_b + 1 * 64, NI, 0 };
        TaskS su { twu, u0, u1, rp_us, rec_us, b_ui + 0 * 64,
                   ln_g + 0 * 64, ln_b + 0 * 64, NU, iblocks };
        TaskS ss { tws, s0, s1, rp_ss, rec_ss, b_soc + 0 * 64,
                   ln_g + 0 * 64, ln_b + 0 * 64, NU, iblocks + ublocks };
        spmmln3<<<agrid, 256, 0, stream>>>(si, su, ss);
    }

    // ---- layer 1 ----
    {
        // twu = it1 @ W_ui[1]; twi = u1 @ W_ui[1]; tws = s1 @ W_soc[1]
        TaskT ta { out_it, twu, W_ui + 1 * 4096, TIL_I, 0, TB_I };
        TaskT tb { u1,     twi, W_ui + 1 * 4096, TIL_U, TB_I, TB_U };
        TaskT tc { s1,     tws, W_soc + 1 * 4096, TIL_U, TB_I + TB_U, TB_S };
        btab3<<<tgrid, 256, 0, stream>>>(ta, tb, tc);
    }
    {
        TaskS si { twi, out_it, out_it, rp_ud, rec_ud, b_ui + 1 * 64,
                   ln_g + 3 * 64, ln_b + 3 * 64, NI, 0 };
        TaskS su { twu, u1, u2, rp_us, rec_us, b_ui + 1 * 64,
                   ln_g + 2 * 64, ln_b + 2 * 64, NU, iblocks };
        TaskS ss { tws, s1, s2, rp_ss, rec_ss, b_soc + 1 * 64,
                   ln_g + 2 * 64, ln_b + 2 * 64, NU, iblocks + ublocks };
        spmmln3<<<agrid, 256, 0, stream>>>(si, su, ss);
    }
}

// Round 13
// 764.946 us; speedup vs baseline: 1.8702x; 1.0623x over previous
//
#include <hip/hip_runtime.h>
#include <stdint.h>

static constexpr int NU    = 100000;
static constexpr int NI    = 200000;
static constexpr int D     = 64;
static constexpr int E_UI  = 3200000;
static constexpr int E_SOC = 1600000;
static constexpr int CH    = 8192;   // edges per binning block
static constexpr int BROWS = 512;    // rows per bucket
#define EPS_LN 1e-5f

typedef __attribute__((ext_vector_type(8))) short bf16x8;
typedef __attribute__((ext_vector_type(4))) float f32x4;

__device__ __forceinline__ unsigned short f2b(float f) {
    unsigned u = __float_as_uint(f);
    u = (u + 0x7FFFu + ((u >> 16) & 1u)) >> 16;   // RNE
    return (unsigned short)u;
}
__device__ __forceinline__ float b2fs(unsigned short h) {
    return __uint_as_float((unsigned)h << 16);
}
__device__ __forceinline__ float b2f_lo(unsigned u) { return __uint_as_float(u << 16); }
__device__ __forceinline__ float b2f_hi(unsigned u) { return __uint_as_float(u & 0xFFFF0000u); }

__device__ __forceinline__ void fma8(float* a, float w, uint4 h) {
    a[0] += w * b2f_lo(h.x); a[1] += w * b2f_hi(h.x);
    a[2] += w * b2f_lo(h.y); a[3] += w * b2f_hi(h.y);
    a[4] += w * b2f_lo(h.z); a[5] += w * b2f_hi(h.z);
    a[6] += w * b2f_lo(h.w); a[7] += w * b2f_hi(h.w);
}

// ================= CSR build: 3 graphs merged per phase =================
struct CntT { const int* rows; int E; int nblk; int nb; int* cnt; int blk0; };

__global__ void __launch_bounds__(256) bin_count3(CntT c0, CntT c1, CntT c2)
{
    __shared__ int hist[512];
    CntT c = (blockIdx.x >= (unsigned)c2.blk0) ? c2
           : (blockIdx.x >= (unsigned)c1.blk0) ? c1 : c0;
    int b = blockIdx.x - c.blk0, t = threadIdx.x;
    for (int i = t; i < c.nb; i += 256) hist[i] = 0;
    __syncthreads();
    int e0 = b * CH, e1 = min(c.E, e0 + CH);
    for (int e = e0 + t; e < e1; e += 256)
        atomicAdd(&hist[c.rows[e] >> 9], 1);
    __syncthreads();
    for (int i = t; i < c.nb; i += 256) c.cnt[i * c.nblk + b] = hist[i];
}

struct ScanT { const int* cnt; int n; int* bsum; int* ofs; int blk0; };

__global__ void scan_partial3(ScanT s0, ScanT s1, ScanT s2)
{
    __shared__ int lds[256];
    ScanT s = (blockIdx.x >= (unsigned)s2.blk0) ? s2
            : (blockIdx.x >= (unsigned)s1.blk0) ? s1 : s0;
    int bb = blockIdx.x - s.blk0;
    int i = bb * 256 + threadIdx.x;
    lds[threadIdx.x] = (i < s.n) ? s.cnt[i] : 0;
    __syncthreads();
    for (int off = 128; off > 0; off >>= 1) {
        if (threadIdx.x < off) lds[threadIdx.x] += lds[threadIdx.x + off];
        __syncthreads();
    }
    if (threadIdx.x == 0) s.bsum[bb] = lds[0];
}

__global__ void scan_bsums3(ScanT s0, ScanT s1, ScanT s2)
{
    __shared__ int lds[1024];
    ScanT s = (blockIdx.x == 2) ? s2 : (blockIdx.x == 1) ? s1 : s0;
    int nb = (s.n + 255) / 256;
    int t = threadIdx.x;
    int v = (t < nb) ? s.bsum[t] : 0;
    lds[t] = v;
    __syncthreads();
    for (int off = 1; off < 1024; off <<= 1) {
        int add = (t >= off) ? lds[t - off] : 0;
        __syncthreads();
        lds[t] += add;
        __syncthreads();
    }
    if (t < nb) s.bsum[t] = lds[t] - v;
}

__global__ void scan_out3(ScanT s0, ScanT s1, ScanT s2)
{
    __shared__ int lds[256];
    ScanT s = (blockIdx.x >= (unsigned)s2.blk0) ? s2
            : (blockIdx.x >= (unsigned)s1.blk0) ? s1 : s0;
    int bb = blockIdx.x - s.blk0;
    int i = bb * 256 + threadIdx.x;
    int v = (i < s.n) ? s.cnt[i] : 0;
    lds[threadIdx.x] = v;
    __syncthreads();
    for (int off = 1; off < 256; off <<= 1) {
        int add = (threadIdx.x >= off) ? lds[threadIdx.x - off] : 0;
        __syncthreads();
        lds[threadIdx.x] += add;
        __syncthreads();
    }
    if (i < s.n) s.ofs[i] = s.bsum[bb] + lds[threadIdx.x] - v;
}

struct ScatT { const int* rows; const int* idxs; const float* vals;
               int E; int nblk; const int* ofs; int nb; int2* binned; int blk0; };

__global__ void __launch_bounds__(256) bin_scatter3(ScatT c0, ScatT c1, ScatT c2)
{
    __shared__ int cur[512];
    ScatT c = (blockIdx.x >= (unsigned)c2.blk0) ? c2
            : (blockIdx.x >= (unsigned)c1.blk0) ? c1 : c0;
    int b = blockIdx.x - c.blk0, t = threadIdx.x;
    for (int i = t; i < c.nb; i += 256) cur[i] = c.ofs[i * c.nblk + b];
    __syncthreads();
    int e0 = b * CH, e1 = min(c.E, e0 + CH);
    for (int e = e0 + t; e < e1; e += 256) {
        int row = c.rows[e];
        int bucket = row >> 9;
        int slot = atomicAdd(&cur[bucket], 1);
        unsigned pack = ((unsigned)(row & 511) << 23) | (unsigned)c.idxs[e];
        c.binned[slot] = make_int2((int)pack, __float_as_int(c.vals[e]));
    }
}

struct FineT { const int2* binned; const int* ofs; int nblk; int nb;
               int E; int nrows; int* rowptr; int2* rec; int blk0; };

__global__ void __launch_bounds__(512) fine_scatter3(FineT c0, FineT c1, FineT c2)
{
    __shared__ int hist[512];
    __shared__ int cur[512];
    FineT c = (blockIdx.x >= (unsigned)c2.blk0) ? c2
            : (blockIdx.x >= (unsigned)c1.blk0) ? c1 : c0;
    int b = blockIdx.x - c.blk0, t = threadIdx.x;
    int beg = c.ofs[b * c.nblk];
    int end = (b + 1 < c.nb) ? c.ofs[(b + 1) * c.nblk] : c.E;

    hist[t] = 0;
    __syncthreads();
    for (int j = beg + t; j < end; j += 512)
        atomicAdd(&hist[((unsigned)c.binned[j].x) >> 23], 1);
    __syncthreads();
    int v = hist[t];
    for (int off = 1; off < 512; off <<= 1) {
        int add = (t >= off) ? hist[t - off] : 0;
        __syncthreads();
        hist[t] += add;
        __syncthreads();
    }
    int excl = hist[t] - v;
    cur[t] = excl;
    int grow = b * BROWS + t;
    if (grow <= c.nrows) c.rowptr[grow] = beg + excl;
    __syncthreads();
    for (int j = beg + t; j < end; j += 512) {
        int2 eb = c.binned[j];
        unsigned p = (unsigned)eb.x;
        int rl  = (int)(p >> 23);
        int idx = (int)(p & 0x7FFFFFu);
        int cc = atomicAdd(&cur[rl], 1);
        c.rec[beg + cc] = make_int2(idx, eb.y);
    }
}

__global__ void copy0_kernel(const float4* __restrict__ src, float4* __restrict__ a,
                             float4* __restrict__ b, int n4)
{
    int i = blockIdx.x * blockDim.x + threadIdx.x;
    if (i < n4) { float4 v = src[i]; a[i] = v; b[i] = v; }
}

// ---------- table GEMM: tab = bf16(X @ W), MFMA hi/lo split ----------
struct TaskT {
    const float* x;
    unsigned short* tab;
    const float* W;
    int ntiles;
    int blk0;
    int nblk;
};

__device__ __forceinline__ void split_hi_lo(const f32x4 a, const f32x4 b,
                                            bf16x8& hi, bf16x8& lo)
{
    #pragma unroll
    for (int j = 0; j < 4; ++j) {
        unsigned short h = f2b(a[j]);
        hi[j] = (short)h;
        lo[j] = (short)f2b(a[j] - b2fs(h));
    }
    #pragma unroll
    for (int j = 0; j < 4; ++j) {
        unsigned short h = f2b(b[j]);
        hi[4 + j] = (short)h;
        lo[4 + j] = (short)f2b(b[j] - b2fs(h));
    }
}

__global__ void __launch_bounds__(256) btab3(TaskT t0, TaskT t1, TaskT t2)
{
    __shared__ float Wl[64 * 64];
    TaskT t = (blockIdx.x >= (unsigned)t2.blk0) ? t2
            : (blockIdx.x >= (unsigned)t1.blk0) ? t1 : t0;
    {
        const float4* W4 = (const float4*)t.W;
        float4* Wl4 = (float4*)Wl;
        for (int i = threadIdx.x; i < 1024; i += 256) Wl4[i] = W4[i];
    }
    __syncthreads();

    int wv   = threadIdx.x >> 6;
    int lane = threadIdx.x & 63;
    int g    = lane >> 4;
    int c    = lane & 15;

    bf16x8 Whi[2][4], Wlo[2][4];
    #pragma unroll
    for (int kt = 0; kt < 2; ++kt)
        #pragma unroll
        for (int nt = 0; nt < 4; ++nt)
            #pragma unroll
            for (int j = 0; j < 8; ++j) {
                float w = Wl[(kt * 32 + 8 * g + j) * 64 + nt * 16 + c];
                unsigned short h = f2b(w);
                Whi[kt][nt][j] = (short)h;
                Wlo[kt][nt][j] = (short)f2b(w - b2fs(h));
            }

    int stride = t.nblk * 4;
    for (int tile = (blockIdx.x - t.blk0) * 4 + wv; tile < t.ntiles; tile += stride) {
        int rowbase = tile * 16;
        const float* arow = t.x + (size_t)(rowbase + c) * 64 + 8 * g;
        f32x4 a00 = *(const f32x4*)(arow);
        f32x4 a01 = *(const f32x4*)(arow + 4);
        f32x4 a10 = *(const f32x4*)(arow + 32);
        f32x4 a11 = *(const f32x4*)(arow + 36);
        bf16x8 Ahi0, Alo0, Ahi1, Alo1;
        split_hi_lo(a00, a01, Ahi0, Alo0);
        split_hi_lo(a10, a11, Ahi1, Alo1);

        #pragma unroll
        for (int nt = 0; nt < 4; ++nt) {
            f32x4 z = {0.f, 0.f, 0.f, 0.f};
            z = __builtin_amdgcn_mfma_f32_16x16x32_bf16(Ahi0, Whi[0][nt], z, 0, 0, 0);
            z = __builtin_amdgcn_mfma_f32_16x16x32_bf16(Ahi1, Whi[1][nt], z, 0, 0, 0);
            z = __builtin_amdgcn_mfma_f32_16x16x32_bf16(Alo0, Whi[0][nt], z, 0, 0, 0);
            z = __builtin_amdgcn_mfma_f32_16x16x32_bf16(Alo1, Whi[1][nt], z, 0, 0, 0);
            z = __builtin_amdgcn_mfma_f32_16x16x32_bf16(Ahi0, Wlo[0][nt], z, 0, 0, 0);
            z = __builtin_amdgcn_mfma_f32_16x16x32_bf16(Ahi1, Wlo[1][nt], z, 0, 0, 0);
            #pragma unroll
            for (int reg = 0; reg < 4; ++reg)
                t.tab[(size_t)(rowbase + 4 * g + reg) * 64 + nt * 16 + c] = f2b(z[reg]);
        }
    }
}

// ---------- fused SpMM(pre-transformed table) + bias + residual + LN ----------
// Batched gather: load up to 4 recs first, then 4 independent row gathers.
struct TaskS {
    const unsigned short* gsrc;
    const float* xin;
    float* yout;
    const int* rowptr;
    const int2* recs;
    const float* bias;
    const float* gamma;
    const float* beta;
    int nrows;
    int blk0;
};

__global__ void __launch_bounds__(256) spmmln3(TaskS t0, TaskS t1, TaskS t2)
{
    TaskS t = (blockIdx.x >= (unsigned)t2.blk0) ? t2
            : (blockIdx.x >= (unsigned)t1.blk0) ? t1 : t0;
    int wid  = (blockIdx.x - t.blk0) * 4 + (threadIdx.x >> 6);
    int lane = threadIdx.x & 63;
    if (wid >= t.nrows) return;

    int g  = lane >> 3;   // edge sub-group 0..7
    int l8 = lane & 7;    // ushort8 slot (dims 8*l8 .. 8*l8+7)

    float accA[8], accB[8];
    #pragma unroll
    for (int m = 0; m < 8; ++m) { accA[m] = 0.f; accB[m] = 0.f; }

    int beg = t.rowptr[wid], end = t.rowptr[wid + 1];
    int jb = beg;
    // full 32-edge batches: 4 recs then 4 gathers, all independent
    for (; jb + 32 <= end; jb += 32) {
        int2 r0 = t.recs[jb + g];
        int2 r1 = t.recs[jb + 8 + g];
        int2 r2 = t.recs[jb + 16 + g];
        int2 r3 = t.recs[jb + 24 + g];
        uint4 h0 = ((const uint4*)(t.gsrc + (size_t)r0.x * 64))[l8];
        uint4 h1 = ((const uint4*)(t.gsrc + (size_t)r1.x * 64))[l8];
        uint4 h2 = ((const uint4*)(t.gsrc + (size_t)r2.x * 64))[l8];
        uint4 h3 = ((const uint4*)(t.gsrc + (size_t)r3.x * 64))[l8];
        fma8(accA, __int_as_float(r0.y), h0);
        fma8(accB, __int_as_float(r1.y), h1);
        fma8(accA, __int_as_float(r2.y), h2);
        fma8(accB, __int_as_float(r3.y), h3);
    }
    int rem = end - jb;
    if (rem > 0) {
        int endm1 = end - 1;
        int e0 = jb + g;
        int2 r0 = t.recs[min(e0, endm1)];
        float w0 = (e0 < end) ? __int_as_float(r0.y) : 0.f;
        int2 r1, r2, r3;
        float w1 = 0.f, w2 = 0.f, w3 = 0.f;
        bool s1 = rem > 8, s2 = rem > 16, s3 = rem > 24;
        if (s1) { int e = jb + 8 + g;  r1 = t.recs[min(e, endm1)]; w1 = (e < end) ? __int_as_float(r1.y) : 0.f; }
        if (s2) { int e = jb + 16 + g; r2 = t.recs[min(e, endm1)]; w2 = (e < end) ? __int_as_float(r2.y) : 0.f; }
        if (s3) { int e = jb + 24 + g; r3 = t.recs[min(e, endm1)]; w3 = (e < end) ? __int_as_float(r3.y) : 0.f; }
        uint4 h0 = ((const uint4*)(t.gsrc + (size_t)r0.x * 64))[l8];
        if (s1) { uint4 h1 = ((const uint4*)(t.gsrc + (size_t)r1.x * 64))[l8]; fma8(accB, w1, h1); }
        if (s2) { uint4 h2 = ((const uint4*)(t.gsrc + (size_t)r2.x * 64))[l8]; fma8(accA, w2, h2); }
        if (s3) { uint4 h3 = ((const uint4*)(t.gsrc + (size_t)r3.x * 64))[l8]; fma8(accB, w3, h3); }
        fma8(accA, w0, h0);
    }
    float acc[8];
    #pragma unroll
    for (int m = 0; m < 8; ++m) acc[m] = accA[m] + accB[m];
    #pragma unroll
    for (int off = 8; off <= 32; off <<= 1)
        #pragma unroll
        for (int m = 0; m < 8; ++m)
            acc[m] += __shfl_xor(acc[m], off);
    // all lanes hold acc for dims 8*l8+m (replicated across g)

    // residual + bias + LayerNorm
    const float4* xi = (const float4*)(t.xin + (size_t)wid * 64 + 8 * l8);
    const float4* bi = (const float4*)(t.bias + 8 * l8);
    float4 x0 = xi[0], x1 = xi[1];
    float4 bb0 = bi[0], bb1 = bi[1];
    float tv[8];
    tv[0] = x0.x + acc[0] + bb0.x; tv[1] = x0.y + acc[1] + bb0.y;
    tv[2] = x0.z + acc[2] + bb0.z; tv[3] = x0.w + acc[3] + bb0.w;
    tv[4] = x1.x + acc[4] + bb1.x; tv[5] = x1.y + acc[5] + bb1.y;
    tv[6] = x1.z + acc[6] + bb1.z; tv[7] = x1.w + acc[7] + bb1.w;

    float s = 0.f;
    #pragma unroll
    for (int m = 0; m < 8; ++m) s += tv[m];
    #pragma unroll
    for (int off = 1; off <= 4; off <<= 1) s += __shfl_xor(s, off);
    float mean = s * (1.0f / 64.0f);
    float q = 0.f;
    #pragma unroll
    for (int m = 0; m < 8; ++m) { float dv = tv[m] - mean; q += dv * dv; }
    #pragma unroll
    for (int off = 1; off <= 4; off <<= 1) q += __shfl_xor(q, off);
    float rs = rsqrtf(q * (1.0f / 64.0f) + EPS_LN);

    if (g == 0) {
        const float4* ga = (const float4*)(t.gamma + 8 * l8);
        const float4* be = (const float4*)(t.beta + 8 * l8);
        float4 g0 = ga[0], g1 = ga[1];
        float4 e0 = be[0], e1 = be[1];
        float4 y0, y1;
        y0.x = (tv[0] - mean) * rs * g0.x + e0.x;
        y0.y = (tv[1] - mean) * rs * g0.y + e0.y;
        y0.z = (tv[2] - mean) * rs * g0.z + e0.z;
        y0.w = (tv[3] - mean) * rs * g0.w + e0.w;
        y1.x = (tv[4] - mean) * rs * g1.x + e1.x;
        y1.y = (tv[5] - mean) * rs * g1.y + e1.y;
        y1.z = (tv[6] - mean) * rs * g1.z + e1.z;
        y1.w = (tv[7] - mean) * rs * g1.w + e1.w;
        float4* yo = (float4*)(t.yout + (size_t)wid * 64 + 8 * l8);
        yo[0] = y0;
        yo[1] = y1;
    }
}

extern "C" void kernel_launch(void* const* d_in, const int* in_sizes, int n_in,
                              void* d_out, int out_size, void* d_ws, size_t ws_size,
                              hipStream_t stream)
{
    const float* user_emb = (const float*)d_in[0];
    const float* item_emb = (const float*)d_in[1];
    const int*   ui_src   = (const int*)d_in[2];
    const int*   ui_dst   = (const int*)d_in[3];
    const float* ui_val   = (const float*)d_in[4];
    const int*   soc_src  = (const int*)d_in[5];
    const int*   soc_dst  = (const int*)d_in[6];
    const float* soc_val  = (const float*)d_in[7];
    const float* W_ui     = (const float*)d_in[8];
    const float* b_ui     = (const float*)d_in[9];
    const float* W_soc    = (const float*)d_in[10];
    const float* b_soc    = (const float*)d_in[11];
    const float* ln_g     = (const float*)d_in[12];
    const float* ln_b     = (const float*)d_in[13];

    float* out     = (float*)d_out;
    float* out_ui  = out;                         // [3][NU][D]
    float* out_soc = out + (size_t)3 * NU * D;    // [3][NU][D]
    float* out_it  = out + (size_t)6 * NU * D;    // [NI][D]

    const int NBU = (NU + BROWS - 1) / BROWS;     // 196
    const int NBI = (NI + BROWS - 1) / BROWS;     // 391
    const int BLK_UI  = (E_UI  + CH - 1) / CH;    // 391
    const int BLK_SOC = (E_SOC + CH - 1) / CH;    // 196

    const int N1 = NBU * BLK_UI;    // 76636
    const int N2 = NBI * BLK_UI;    // 152881
    const int N3 = NBU * BLK_SOC;   // 38416
    const int SB1 = (N1 + 255) / 256, SB2 = (N2 + 255) / 256, SB3 = (N3 + 255) / 256;

    // ---- workspace carve (256B-aligned) ----
    char* p = (char*)d_ws;
    auto take = [&](size_t bytes) { char* r = p; p += (bytes + 255) & ~(size_t)255; return r; };
    int2* rec_us = (int2*)take((size_t)E_UI * 8);
    int2* rec_ud = (int2*)take((size_t)E_UI * 8);
    int2* rec_ss = (int2*)take((size_t)E_SOC * 8);
    int2* bin1 = (int2*)take((size_t)E_UI * 8);    // reused as twu after CSR build
    int2* bin2 = (int2*)take((size_t)E_UI * 8);
    int2* bin3 = (int2*)take((size_t)E_SOC * 8);
    int*  rp_us  = (int*)take((size_t)(NU + 1) * 4);
    int*  rp_ud  = (int*)take((size_t)(NI + 1) * 4);
    int*  rp_ss  = (int*)take((size_t)(NU + 1) * 4);
    int*  cnt1 = (int*)take((size_t)N1 * 4);
    int*  cnt2 = (int*)take((size_t)N2 * 4);
    int*  cnt3 = (int*)take((size_t)N3 * 4);
    int*  ofs1 = (int*)take((size_t)N1 * 4);
    int*  ofs2 = (int*)take((size_t)N2 * 4);
    int*  ofs3 = (int*)take((size_t)N3 * 4);
    int*  bs1 = (int*)take(1024 * 4);
    int*  bs2 = (int*)take(1024 * 4);
    int*  bs3 = (int*)take(1024 * 4);
    unsigned short* twi = (unsigned short*)take((size_t)NU * D * 2);  // u_cur @ W_ui
    unsigned short* tws = (unsigned short*)take((size_t)NU * D * 2);  // s_cur @ W_soc
    unsigned short* twu = (unsigned short*)bin1;                      // it_cur @ W_ui (NI rows)

    // ---- CSR build: 6 merged dispatches ----
    {
        CntT c1 { ui_src,  E_UI,  BLK_UI,  NBU, cnt1, 0 };
        CntT c2 { ui_dst,  E_UI,  BLK_UI,  NBI, cnt2, BLK_UI };
        CntT c3 { soc_src, E_SOC, BLK_SOC, NBU, cnt3, 2 * BLK_UI };
        bin_count3<<<2 * BLK_UI + BLK_SOC, 256, 0, stream>>>(c1, c2, c3);
    }
    {
        ScanT s1 { cnt1, N1, bs1, ofs1, 0 };
        ScanT s2 { cnt2, N2, bs2, ofs2, SB1 };
        ScanT s3 { cnt3, N3, bs3, ofs3, SB1 + SB2 };
        scan_partial3<<<SB1 + SB2 + SB3, 256, 0, stream>>>(s1, s2, s3);
        scan_bsums3<<<3, 1024, 0, stream>>>(s1, s2, s3);
        scan_out3<<<SB1 + SB2 + SB3, 256, 0, stream>>>(s1, s2, s3);
    }
    {
        ScatT c1 { ui_src,  ui_dst,  ui_val,  E_UI,  BLK_UI,  ofs1, NBU, bin1, 0 };
        ScatT c2 { ui_dst,  ui_src,  ui_val,  E_UI,  BLK_UI,  ofs2, NBI, bin2, BLK_UI };
        ScatT c3 { soc_src, soc_dst, soc_val, E_SOC, BLK_SOC, ofs3, NBU, bin3, 2 * BLK_UI };
        bin_scatter3<<<2 * BLK_UI + BLK_SOC, 256, 0, stream>>>(c1, c2, c3);
    }
    {
        FineT f1 { bin1, ofs1, BLK_UI,  NBU, E_UI,  NU, rp_us, rec_us, 0 };
        FineT f2 { bin2, ofs2, BLK_UI,  NBI, E_UI,  NI, rp_ud, rec_ud, NBU };
        FineT f3 { bin3, ofs3, BLK_SOC, NBU, E_SOC, NU, rp_ss, rec_ss, NBU + NBI };
        fine_scatter3<<<NBU + NBI + NBU, 512, 0, stream>>>(f1, f2, f3);
    }

    int n4 = NU * D / 4;
    copy0_kernel<<<(n4 + 255) / 256, 256, 0, stream>>>((const float4*)user_emb,
                                                       (float4*)out_ui, (float4*)out_soc, n4);

    const float* u0 = user_emb;
    float* u1 = out_ui + (size_t)NU * D;
    float* u2 = out_ui + (size_t)2 * NU * D;
    const float* s0 = user_emb;
    float* s1 = out_soc + (size_t)NU * D;
    float* s2 = out_soc + (size_t)2 * NU * D;

    int ublocks = (NU + 3) / 4;   // 25000
    int iblocks = (NI + 3) / 4;   // 50000
    int agrid   = iblocks + 2 * ublocks;

    const int TB_I = 1040, TB_U = 520, TB_S = 520;
    int tgrid = TB_I + TB_U + TB_S;
    const int TIL_I = NI / 16, TIL_U = NU / 16;   // 12500, 6250

    // ---- layer 0 ----
    {
        TaskT ta { item_emb, twu, W_ui + 0 * 4096, TIL_I, 0, TB_I };
        TaskT tb { u0,       twi, W_ui + 0 * 4096, TIL_U, TB_I, TB_U };
        TaskT tc { u0,       tws, W_soc + 0 * 4096, TIL_U, TB_I + TB_U, TB_S };
        btab3<<<tgrid, 256, 0, stream>>>(ta, tb, tc);
    }
    {
        TaskS si { twi, item_emb, out_it, rp_ud, rec_ud, b_ui + 0 * 64,
                   ln_g + 1 * 64, ln_b + 1 * 64, NI, 0 };
        TaskS su { twu, u0, u1, rp_us, rec_us, b_ui + 0 * 64,
                   ln_g + 0 * 64, ln_b + 0 * 64, NU, iblocks };
        TaskS ss { tws, s0, s1, rp_ss, rec_ss, b_soc + 0 * 64,
                   ln_g + 0 * 64, ln_b + 0 * 64, NU, iblocks + ublocks };
        spmmln3<<<agrid, 256, 0, stream>>>(si, su, ss);
    }

    // ---- layer 1 ----
    {
        TaskT ta { out_it, twu, W_ui + 1 * 4096, TIL_I, 0, TB_I };
        TaskT tb { u1,     twi, W_ui + 1 * 4096, TIL_U, TB_I, TB_U };
        TaskT tc { s1,     tws, W_soc + 1 * 4096, TIL_U, TB_I + TB_U, TB_S };
        btab3<<<tgrid, 256, 0, stream>>>(ta, tb, tc);
    }
    {
        TaskS si { twi, out_it, out_it, rp_ud, rec_ud, b_ui + 1 * 64,
                   ln_g + 3 * 64, ln_b + 3 * 64, NI, 0 };
        TaskS su { twu, u1, u2, rp_us, rec_us, b_ui + 1 * 64,
                   ln_g + 2 * 64, ln_b + 2 * 64, NU, iblocks };
        TaskS ss { tws, s1, s2, rp_ss, rec_ss, b_soc + 1 * 64,
                   ln_g + 2 * 64, ln_b + 2 * 64, NU, iblocks + ublocks };
        spmmln3<<<agrid, 256, 0, stream>>>(si, su, ss);
    }
}

// Round 15
// 680.703 us; speedup vs baseline: 2.1016x; 1.1238x over previous
//
#include <hip/hip_runtime.h>
#include <stdint.h>

static constexpr int NU    = 100000;
static constexpr int NI    = 200000;
static constexpr int D     = 64;
static constexpr int E_UI  = 3200000;
static constexpr int E_SOC = 1600000;
static constexpr int CH    = 8192;   // edges per binning block
static constexpr int BROWS = 512;    // rows per bucket
#define EPS_LN 1e-5f

typedef __attribute__((ext_vector_type(8))) short bf16x8;
typedef __attribute__((ext_vector_type(4))) float f32x4;

__device__ __forceinline__ unsigned short f2b(float f) {
    unsigned u = __float_as_uint(f);
    u = (u + 0x7FFFu + ((u >> 16) & 1u)) >> 16;   // RNE
    return (unsigned short)u;
}
__device__ __forceinline__ float b2fs(unsigned short h) {
    return __uint_as_float((unsigned)h << 16);
}
__device__ __forceinline__ float b2f_lo(unsigned u) { return __uint_as_float(u << 16); }
__device__ __forceinline__ float b2f_hi(unsigned u) { return __uint_as_float(u & 0xFFFF0000u); }

__device__ __forceinline__ void fma8(float* a, float w, uint4 h) {
    a[0] += w * b2f_lo(h.x); a[1] += w * b2f_hi(h.x);
    a[2] += w * b2f_lo(h.y); a[3] += w * b2f_hi(h.y);
    a[4] += w * b2f_lo(h.z); a[5] += w * b2f_hi(h.z);
    a[6] += w * b2f_lo(h.w); a[7] += w * b2f_hi(h.w);
}

// ================= CSR build: 3 graphs merged per phase =================
struct CntT { const int* rows; int E; int nblk; int nb; int* cnt; int blk0; };

__global__ void __launch_bounds__(256) bin_count3(CntT c0, CntT c1, CntT c2)
{
    __shared__ int hist[512];
    CntT c = (blockIdx.x >= (unsigned)c2.blk0) ? c2
           : (blockIdx.x >= (unsigned)c1.blk0) ? c1 : c0;
    int b = blockIdx.x - c.blk0, t = threadIdx.x;
    for (int i = t; i < c.nb; i += 256) hist[i] = 0;
    __syncthreads();
    int e0 = b * CH, e1 = min(c.E, e0 + CH);
    for (int e = e0 + t; e < e1; e += 256)
        atomicAdd(&hist[c.rows[e] >> 9], 1);
    __syncthreads();
    for (int i = t; i < c.nb; i += 256) c.cnt[i * c.nblk + b] = hist[i];
}

struct ScanT { const int* cnt; int n; int* bsum; int* ofs; int blk0; };

__global__ void scan_partial3(ScanT s0, ScanT s1, ScanT s2)
{
    __shared__ int lds[256];
    ScanT s = (blockIdx.x >= (unsigned)s2.blk0) ? s2
            : (blockIdx.x >= (unsigned)s1.blk0) ? s1 : s0;
    int bb = blockIdx.x - s.blk0;
    int i = bb * 256 + threadIdx.x;
    lds[threadIdx.x] = (i < s.n) ? s.cnt[i] : 0;
    __syncthreads();
    for (int off = 128; off > 0; off >>= 1) {
        if (threadIdx.x < off) lds[threadIdx.x] += lds[threadIdx.x + off];
        __syncthreads();
    }
    if (threadIdx.x == 0) s.bsum[bb] = lds[0];
}

__global__ void scan_bsums3(ScanT s0, ScanT s1, ScanT s2)
{
    __shared__ int lds[1024];
    ScanT s = (blockIdx.x == 2) ? s2 : (blockIdx.x == 1) ? s1 : s0;
    int nb = (s.n + 255) / 256;
    int t = threadIdx.x;
    int v = (t < nb) ? s.bsum[t] : 0;
    lds[t] = v;
    __syncthreads();
    for (int off = 1; off < 1024; off <<= 1) {
        int add = (t >= off) ? lds[t - off] : 0;
        __syncthreads();
        lds[t] += add;
        __syncthreads();
    }
    if (t < nb) s.bsum[t] = lds[t] - v;
}

__global__ void scan_out3(ScanT s0, ScanT s1, ScanT s2)
{
    __shared__ int lds[256];
    ScanT s = (blockIdx.x >= (unsigned)s2.blk0) ? s2
            : (blockIdx.x >= (unsigned)s1.blk0) ? s1 : s0;
    int bb = blockIdx.x - s.blk0;
    int i = bb * 256 + threadIdx.x;
    int v = (i < s.n) ? s.cnt[i] : 0;
    lds[threadIdx.x] = v;
    __syncthreads();
    for (int off = 1; off < 256; off <<= 1) {
        int add = (threadIdx.x >= off) ? lds[threadIdx.x - off] : 0;
        __syncthreads();
        lds[threadIdx.x] += add;
        __syncthreads();
    }
    if (i < s.n) s.ofs[i] = s.bsum[bb] + lds[threadIdx.x] - v;
}

struct ScatT { const int* rows; const int* idxs; const float* vals;
               int E; int nblk; const int* ofs; int nb; int2* binned; int blk0; };

__global__ void __launch_bounds__(256) bin_scatter3(ScatT c0, ScatT c1, ScatT c2)
{
    __shared__ int cur[512];
    ScatT c = (blockIdx.x >= (unsigned)c2.blk0) ? c2
            : (blockIdx.x >= (unsigned)c1.blk0) ? c1 : c0;
    int b = blockIdx.x - c.blk0, t = threadIdx.x;
    for (int i = t; i < c.nb; i += 256) cur[i] = c.ofs[i * c.nblk + b];
    __syncthreads();
    int e0 = b * CH, e1 = min(c.E, e0 + CH);
    for (int e = e0 + t; e < e1; e += 256) {
        int row = c.rows[e];
        int bucket = row >> 9;
        int slot = atomicAdd(&cur[bucket], 1);
        unsigned pack = ((unsigned)(row & 511) << 23) | (unsigned)c.idxs[e];
        c.binned[slot] = make_int2((int)pack, __float_as_int(c.vals[e]));
    }
}

struct FineT { const int2* binned; const int* ofs; int nblk; int nb;
               int E; int nrows; int* rowptr; int2* rec; int blk0; };

__global__ void __launch_bounds__(512) fine_scatter3(FineT c0, FineT c1, FineT c2)
{
    __shared__ int hist[512];
    __shared__ int cur[512];
    FineT c = (blockIdx.x >= (unsigned)c2.blk0) ? c2
            : (blockIdx.x >= (unsigned)c1.blk0) ? c1 : c0;
    int b = blockIdx.x - c.blk0, t = threadIdx.x;
    int beg = c.ofs[b * c.nblk];
    int end = (b + 1 < c.nb) ? c.ofs[(b + 1) * c.nblk] : c.E;

    hist[t] = 0;
    __syncthreads();
    for (int j = beg + t; j < end; j += 512)
        atomicAdd(&hist[((unsigned)c.binned[j].x) >> 23], 1);
    __syncthreads();
    int v = hist[t];
    for (int off = 1; off < 512; off <<= 1) {
        int add = (t >= off) ? hist[t - off] : 0;
        __syncthreads();
        hist[t] += add;
        __syncthreads();
    }
    int excl = hist[t] - v;
    cur[t] = excl;
    int grow = b * BROWS + t;
    if (grow <= c.nrows) c.rowptr[grow] = beg + excl;
    __syncthreads();
    for (int j = beg + t; j < end; j += 512) {
        int2 eb = c.binned[j];
        unsigned p = (unsigned)eb.x;
        int rl  = (int)(p >> 23);
        int idx = (int)(p & 0x7FFFFFu);
        int cc = atomicAdd(&cur[rl], 1);
        c.rec[beg + cc] = make_int2(idx, eb.y);
    }
}

__global__ void copy0_kernel(const float4* __restrict__ src, float4* __restrict__ a,
                             float4* __restrict__ b, int n4)
{
    int i = blockIdx.x * blockDim.x + threadIdx.x;
    if (i < n4) { float4 v = src[i]; a[i] = v; b[i] = v; }
}

// ---------- table GEMM: tab = bf16(X @ W), MFMA hi/lo split ----------
struct TaskT {
    const float* x;
    unsigned short* tab;
    const float* W;
    int ntiles;
    int blk0;
    int nblk;
};

__device__ __forceinline__ void split_hi_lo(const f32x4 a, const f32x4 b,
                                            bf16x8& hi, bf16x8& lo)
{
    #pragma unroll
    for (int j = 0; j < 4; ++j) {
        unsigned short h = f2b(a[j]);
        hi[j] = (short)h;
        lo[j] = (short)f2b(a[j] - b2fs(h));
    }
    #pragma unroll
    for (int j = 0; j < 4; ++j) {
        unsigned short h = f2b(b[j]);
        hi[4 + j] = (short)h;
        lo[4 + j] = (short)f2b(b[j] - b2fs(h));
    }
}

__global__ void __launch_bounds__(256) btab3(TaskT t0, TaskT t1, TaskT t2)
{
    __shared__ float Wl[64 * 64];
    TaskT t = (blockIdx.x >= (unsigned)t2.blk0) ? t2
            : (blockIdx.x >= (unsigned)t1.blk0) ? t1 : t0;
    {
        const float4* W4 = (const float4*)t.W;
        float4* Wl4 = (float4*)Wl;
        for (int i = threadIdx.x; i < 1024; i += 256) Wl4[i] = W4[i];
    }
    __syncthreads();

    int wv   = threadIdx.x >> 6;
    int lane = threadIdx.x & 63;
    int g    = lane >> 4;
    int c    = lane & 15;

    bf16x8 Whi[2][4], Wlo[2][4];
    #pragma unroll
    for (int kt = 0; kt < 2; ++kt)
        #pragma unroll
        for (int nt = 0; nt < 4; ++nt)
            #pragma unroll
            for (int j = 0; j < 8; ++j) {
                float w = Wl[(kt * 32 + 8 * g + j) * 64 + nt * 16 + c];
                unsigned short h = f2b(w);
                Whi[kt][nt][j] = (short)h;
                Wlo[kt][nt][j] = (short)f2b(w - b2fs(h));
            }

    int stride = t.nblk * 4;
    for (int tile = (blockIdx.x - t.blk0) * 4 + wv; tile < t.ntiles; tile += stride) {
        int rowbase = tile * 16;
        const float* arow = t.x + (size_t)(rowbase + c) * 64 + 8 * g;
        f32x4 a00 = *(const f32x4*)(arow);
        f32x4 a01 = *(const f32x4*)(arow + 4);
        f32x4 a10 = *(const f32x4*)(arow + 32);
        f32x4 a11 = *(const f32x4*)(arow + 36);
        bf16x8 Ahi0, Alo0, Ahi1, Alo1;
        split_hi_lo(a00, a01, Ahi0, Alo0);
        split_hi_lo(a10, a11, Ahi1, Alo1);

        #pragma unroll
        for (int nt = 0; nt < 4; ++nt) {
            f32x4 z = {0.f, 0.f, 0.f, 0.f};
            z = __builtin_amdgcn_mfma_f32_16x16x32_bf16(Ahi0, Whi[0][nt], z, 0, 0, 0);
            z = __builtin_amdgcn_mfma_f32_16x16x32_bf16(Ahi1, Whi[1][nt], z, 0, 0, 0);
            z = __builtin_amdgcn_mfma_f32_16x16x32_bf16(Alo0, Whi[0][nt], z, 0, 0, 0);
            z = __builtin_amdgcn_mfma_f32_16x16x32_bf16(Alo1, Whi[1][nt], z, 0, 0, 0);
            z = __builtin_amdgcn_mfma_f32_16x16x32_bf16(Ahi0, Wlo[0][nt], z, 0, 0, 0);
            z = __builtin_amdgcn_mfma_f32_16x16x32_bf16(Ahi1, Wlo[1][nt], z, 0, 0, 0);
            #pragma unroll
            for (int reg = 0; reg < 4; ++reg)
                t.tab[(size_t)(rowbase + 4 * g + reg) * 64 + nt * 16 + c] = f2b(z[reg]);
        }
    }
}

// ---------- fused SpMM(pre-transformed table) + bias + residual + LN ----------
// 2 rows per wave (32 lanes/row): 4 edge-groups x 8 lanes x 16B; 4-deep batch
// (16 edges in flight per row); tail = 4 exec-mask-predicated slots.
struct TaskS {
    const unsigned short* gsrc;
    const float* xin;
    float* yout;
    const int* rowptr;
    const int2* recs;
    const float* bias;
    const float* gamma;
    const float* beta;
    int nrows;
    int blk0;
};

__global__ void __launch_bounds__(256) spmmln3(TaskS t0, TaskS t1, TaskS t2)
{
    TaskS t = (blockIdx.x >= (unsigned)t2.blk0) ? t2
            : (blockIdx.x >= (unsigned)t1.blk0) ? t1 : t0;
    int wid2 = (blockIdx.x - t.blk0) * 4 + (threadIdx.x >> 6);   // wave index
    int lane = threadIdx.x & 63;
    int half = lane >> 5;          // row within wave
    int row  = wid2 * 2 + half;
    if (row >= t.nrows) return;    // nrows even -> whole waves exit

    int g4 = (lane >> 3) & 3;      // edge sub-group 0..3 (within 32-lane half)
    int l8 = lane & 7;             // ushort8 slot (dims 8*l8 .. 8*l8+7)

    float accA[8], accB[8];
    #pragma unroll
    for (int m = 0; m < 8; ++m) { accA[m] = 0.f; accB[m] = 0.f; }

    int beg = t.rowptr[row], end = t.rowptr[row + 1];
    int jb = beg;
    for (; jb + 16 <= end; jb += 16) {
        int2 r0 = t.recs[jb + g4];
        int2 r1 = t.recs[jb + 4 + g4];
        int2 r2 = t.recs[jb + 8 + g4];
        int2 r3 = t.recs[jb + 12 + g4];
        uint4 h0 = ((const uint4*)(t.gsrc + (size_t)r0.x * 64))[l8];
        uint4 h1 = ((const uint4*)(t.gsrc + (size_t)r1.x * 64))[l8];
        uint4 h2 = ((const uint4*)(t.gsrc + (size_t)r2.x * 64))[l8];
        uint4 h3 = ((const uint4*)(t.gsrc + (size_t)r3.x * 64))[l8];
        fma8(accA, __int_as_float(r0.y), h0);
        fma8(accB, __int_as_float(r1.y), h1);
        fma8(accA, __int_as_float(r2.y), h2);
        fma8(accB, __int_as_float(r3.y), h3);
    }
    if (jb < end) {
        int endm1 = end - 1;       // >= jb >= 0 here
        int e0 = jb + g4, e1 = jb + 4 + g4, e2 = jb + 8 + g4, e3 = jb + 12 + g4;
        int2 r0 = t.recs[min(e0, endm1)];
        int2 r1 = t.recs[min(e1, endm1)];
        int2 r2 = t.recs[min(e2, endm1)];
        int2 r3 = t.recs[min(e3, endm1)];
        if (e0 < end) { uint4 h = ((const uint4*)(t.gsrc + (size_t)r0.x * 64))[l8]; fma8(accA, __int_as_float(r0.y), h); }
        if (e1 < end) { uint4 h = ((const uint4*)(t.gsrc + (size_t)r1.x * 64))[l8]; fma8(accB, __int_as_float(r1.y), h); }
        if (e2 < end) { uint4 h = ((const uint4*)(t.gsrc + (size_t)r2.x * 64))[l8]; fma8(accA, __int_as_float(r2.y), h); }
        if (e3 < end) { uint4 h = ((const uint4*)(t.gsrc + (size_t)r3.x * 64))[l8]; fma8(accB, __int_as_float(r3.y), h); }
    }
    float acc[8];
    #pragma unroll
    for (int m = 0; m < 8; ++m) acc[m] = accA[m] + accB[m];
    // reduce across the 4 edge sub-groups (stays within the 32-lane half)
    #pragma unroll
    for (int off = 8; off <= 16; off <<= 1)
        #pragma unroll
        for (int m = 0; m < 8; ++m)
            acc[m] += __shfl_xor(acc[m], off);
    // all lanes of the half hold acc for dims 8*l8+m

    // residual + bias + LayerNorm
    const float4* xi = (const float4*)(t.xin + (size_t)row * 64 + 8 * l8);
    const float4* bi = (const float4*)(t.bias + 8 * l8);
    float4 x0 = xi[0], x1 = xi[1];
    float4 bb0 = bi[0], bb1 = bi[1];
    float tv[8];
    tv[0] = x0.x + acc[0] + bb0.x; tv[1] = x0.y + acc[1] + bb0.y;
    tv[2] = x0.z + acc[2] + bb0.z; tv[3] = x0.w + acc[3] + bb0.w;
    tv[4] = x1.x + acc[4] + bb1.x; tv[5] = x1.y + acc[5] + bb1.y;
    tv[6] = x1.z + acc[6] + bb1.z; tv[7] = x1.w + acc[7] + bb1.w;

    float s = 0.f;
    #pragma unroll
    for (int m = 0; m < 8; ++m) s += tv[m];
    #pragma unroll
    for (int off = 1; off <= 4; off <<= 1) s += __shfl_xor(s, off);
    float mean = s * (1.0f / 64.0f);
    float q = 0.f;
    #pragma unroll
    for (int m = 0; m < 8; ++m) { float dv = tv[m] - mean; q += dv * dv; }
    #pragma unroll
    for (int off = 1; off <= 4; off <<= 1) q += __shfl_xor(q, off);
    float rs = rsqrtf(q * (1.0f / 64.0f) + EPS_LN);

    if (g4 == 0) {
        const float4* ga = (const float4*)(t.gamma + 8 * l8);
        const float4* be = (const float4*)(t.beta + 8 * l8);
        float4 g0 = ga[0], g1 = ga[1];
        float4 e0 = be[0], e1 = be[1];
        float4 y0, y1;
        y0.x = (tv[0] - mean) * rs * g0.x + e0.x;
        y0.y = (tv[1] - mean) * rs * g0.y + e0.y;
        y0.z = (tv[2] - mean) * rs * g0.z + e0.z;
        y0.w = (tv[3] - mean) * rs * g0.w + e0.w;
        y1.x = (tv[4] - mean) * rs * g1.x + e1.x;
        y1.y = (tv[5] - mean) * rs * g1.y + e1.y;
        y1.z = (tv[6] - mean) * rs * g1.z + e1.z;
        y1.w = (tv[7] - mean) * rs * g1.w + e1.w;
        float4* yo = (float4*)(t.yout + (size_t)row * 64 + 8 * l8);
        yo[0] = y0;
        yo[1] = y1;
    }
}

extern "C" void kernel_launch(void* const* d_in, const int* in_sizes, int n_in,
                              void* d_out, int out_size, void* d_ws, size_t ws_size,
                              hipStream_t stream)
{
    const float* user_emb = (const float*)d_in[0];
    const float* item_emb = (const float*)d_in[1];
    const int*   ui_src   = (const int*)d_in[2];
    const int*   ui_dst   = (const int*)d_in[3];
    const float* ui_val   = (const float*)d_in[4];
    const int*   soc_src  = (const int*)d_in[5];
    const int*   soc_dst  = (const int*)d_in[6];
    const float* soc_val  = (const float*)d_in[7];
    const float* W_ui     = (const float*)d_in[8];
    const float* b_ui     = (const float*)d_in[9];
    const float* W_soc    = (const float*)d_in[10];
    const float* b_soc    = (const float*)d_in[11];
    const float* ln_g     = (const float*)d_in[12];
    const float* ln_b     = (const float*)d_in[13];

    float* out     = (float*)d_out;
    float* out_ui  = out;                         // [3][NU][D]
    float* out_soc = out + (size_t)3 * NU * D;    // [3][NU][D]
    float* out_it  = out + (size_t)6 * NU * D;    // [NI][D]

    const int NBU = (NU + BROWS - 1) / BROWS;     // 196
    const int NBI = (NI + BROWS - 1) / BROWS;     // 391
    const int BLK_UI  = (E_UI  + CH - 1) / CH;    // 391
    const int BLK_SOC = (E_SOC + CH - 1) / CH;    // 196

    const int N1 = NBU * BLK_UI;    // 76636
    const int N2 = NBI * BLK_UI;    // 152881
    const int N3 = NBU * BLK_SOC;   // 38416
    const int SB1 = (N1 + 255) / 256, SB2 = (N2 + 255) / 256, SB3 = (N3 + 255) / 256;

    // ---- workspace carve (256B-aligned) ----
    char* p = (char*)d_ws;
    auto take = [&](size_t bytes) { char* r = p; p += (bytes + 255) & ~(size_t)255; return r; };
    int2* rec_us = (int2*)take((size_t)E_UI * 8);
    int2* rec_ud = (int2*)take((size_t)E_UI * 8);
    int2* rec_ss = (int2*)take((size_t)E_SOC * 8);
    int2* bin1 = (int2*)take((size_t)E_UI * 8);    // reused as twu after CSR build
    int2* bin2 = (int2*)take((size_t)E_UI * 8);
    int2* bin3 = (int2*)take((size_t)E_SOC * 8);
    int*  rp_us  = (int*)take((size_t)(NU + 1) * 4);
    int*  rp_ud  = (int*)take((size_t)(NI + 1) * 4);
    int*  rp_ss  = (int*)take((size_t)(NU + 1) * 4);
    int*  cnt1 = (int*)take((size_t)N1 * 4);
    int*  cnt2 = (int*)take((size_t)N2 * 4);
    int*  cnt3 = (int*)take((size_t)N3 * 4);
    int*  ofs1 = (int*)take((size_t)N1 * 4);
    int*  ofs2 = (int*)take((size_t)N2 * 4);
    int*  ofs3 = (int*)take((size_t)N3 * 4);
    int*  bs1 = (int*)take(1024 * 4);
    int*  bs2 = (int*)take(1024 * 4);
    int*  bs3 = (int*)take(1024 * 4);
    unsigned short* twi = (unsigned short*)take((size_t)NU * D * 2);  // u_cur @ W_ui
    unsigned short* tws = (unsigned short*)take((size_t)NU * D * 2);  // s_cur @ W_soc
    unsigned short* twu = (unsigned short*)bin1;                      // it_cur @ W_ui (NI rows)

    // ---- CSR build: 6 merged dispatches ----
    {
        CntT c1 { ui_src,  E_UI,  BLK_UI,  NBU, cnt1, 0 };
        CntT c2 { ui_dst,  E_UI,  BLK_UI,  NBI, cnt2, BLK_UI };
        CntT c3 { soc_src, E_SOC, BLK_SOC, NBU, cnt3, 2 * BLK_UI };
        bin_count3<<<2 * BLK_UI + BLK_SOC, 256, 0, stream>>>(c1, c2, c3);
    }
    {
        ScanT s1 { cnt1, N1, bs1, ofs1, 0 };
        ScanT s2 { cnt2, N2, bs2, ofs2, SB1 };
        ScanT s3 { cnt3, N3, bs3, ofs3, SB1 + SB2 };
        scan_partial3<<<SB1 + SB2 + SB3, 256, 0, stream>>>(s1, s2, s3);
        scan_bsums3<<<3, 1024, 0, stream>>>(s1, s2, s3);
        scan_out3<<<SB1 + SB2 + SB3, 256, 0, stream>>>(s1, s2, s3);
    }
    {
        ScatT c1 { ui_src,  ui_dst,  ui_val,  E_UI,  BLK_UI,  ofs1, NBU, bin1, 0 };
        ScatT c2 { ui_dst,  ui_src,  ui_val,  E_UI,  BLK_UI,  ofs2, NBI, bin2, BLK_UI };
        ScatT c3 { soc_src, soc_dst, soc_val, E_SOC, BLK_SOC, ofs3, NBU, bin3, 2 * BLK_UI };
        bin_scatter3<<<2 * BLK_UI + BLK_SOC, 256, 0, stream>>>(c1, c2, c3);
    }
    {
        FineT f1 { bin1, ofs1, BLK_UI,  NBU, E_UI,  NU, rp_us, rec_us, 0 };
        FineT f2 { bin2, ofs2, BLK_UI,  NBI, E_UI,  NI, rp_ud, rec_ud, NBU };
        FineT f3 { bin3, ofs3, BLK_SOC, NBU, E_SOC, NU, rp_ss, rec_ss, NBU + NBI };
        fine_scatter3<<<NBU + NBI + NBU, 512, 0, stream>>>(f1, f2, f3);
    }

    int n4 = NU * D / 4;
    copy0_kernel<<<(n4 + 255) / 256, 256, 0, stream>>>((const float4*)user_emb,
                                                       (float4*)out_ui, (float4*)out_soc, n4);

    const float* u0 = user_emb;
    float* u1 = out_ui + (size_t)NU * D;
    float* u2 = out_ui + (size_t)2 * NU * D;
    const float* s0 = user_emb;
    float* s1 = out_soc + (size_t)NU * D;
    float* s2 = out_soc + (size_t)2 * NU * D;

    int ublocks8 = (NU + 7) / 8;   // 12500  (8 rows per 256-thread block)
    int iblocks8 = (NI + 7) / 8;   // 25000
    int agrid    = iblocks8 + 2 * ublocks8;

    const int TB_I = 1040, TB_U = 520, TB_S = 520;
    int tgrid = TB_I + TB_U + TB_S;
    const int TIL_I = NI / 16, TIL_U = NU / 16;   // 12500, 6250

    // ---- layer 0 ----
    {
        TaskT ta { item_emb, twu, W_ui + 0 * 4096, TIL_I, 0, TB_I };
        TaskT tb { u0,       twi, W_ui + 0 * 4096, TIL_U, TB_I, TB_U };
        TaskT tc { u0,       tws, W_soc + 0 * 4096, TIL_U, TB_I + TB_U, TB_S };
        btab3<<<tgrid, 256, 0, stream>>>(ta, tb, tc);
    }
    {
        TaskS si { twi, item_emb, out_it, rp_ud, rec_ud, b_ui + 0 * 64,
                   ln_g + 1 * 64, ln_b + 1 * 64, NI, 0 };
        TaskS su { twu, u0, u1, rp_us, rec_us, b_ui + 0 * 64,
                   ln_g + 0 * 64, ln_b + 0 * 64, NU, iblocks8 };
        TaskS ss { tws, s0, s1, rp_ss, rec_ss, b_soc + 0 * 64,
                   ln_g + 0 * 64, ln_b + 0 * 64, NU, iblocks8 + ublocks8 };
        spmmln3<<<agrid, 256, 0, stream>>>(si, su, ss);
    }

    // ---- layer 1 ----
    {
        TaskT ta { out_it, twu, W_ui + 1 * 4096, TIL_I, 0, TB_I };
        TaskT tb { u1,     twi, W_ui + 1 * 4096, TIL_U, TB_I, TB_U };
        TaskT tc { s1,     tws, W_soc + 1 * 4096, TIL_U, TB_I + TB_U, TB_S };
        btab3<<<tgrid, 256, 0, stream>>>(ta, tb, tc);
    }
    {
        TaskS si { twi, out_it, out_it, rp_ud, rec_ud, b_ui + 1 * 64,
                   ln_g + 3 * 64, ln_b + 3 * 64, NI, 0 };
        TaskS su { twu, u1, u2, rp_us, rec_us, b_ui + 1 * 64,
                   ln_g + 2 * 64, ln_b + 2 * 64, NU, iblocks8 };
        TaskS ss { tws, s1, s2, rp_ss, rec_ss, b_soc + 1 * 64,
                   ln_g + 2 * 64, ln_b + 2 * 64, NU, iblocks8 + ublocks8 };
        spmmln3<<<agrid, 256, 0, stream>>>(si, su, ss);
    }
}